// Round 14
// baseline (248.324 us; speedup 1.0000x reference)
//
#include <hip/hip_runtime.h>
#include <hip/hip_fp16.h>

#define N_NODES 100000
#define N_CAP 100096      // NBUK*128, padded node capacity for tables
#define N_EDGES 1250000
#define N_GRAPHS 64
#define F_INN 29
#define HD 64
#define NT 6
#define GT 4
#define NLAYERS 4
#define NC 4              // source chunks (25000 rows = 3.2 MB fp16, fits 4MB XCD L2)
#define CHUNK_SZ 25000
#define RECS_CAP 3000000  // >= E + 3*NC*N worst-case padded slots
#define NBLK 1563         // ceil(N_NODES / 64) dest-blocks (layer)
#define NBUK 782          // ceil(N_NODES / 128) CSR-build buckets
#define HGRID 256         // blocks in hist/scatter (edge partition)
#define GB_BLOCKS 391     // ceil(N/256) graph_bounds sections
#define ENC_BLOCKS 6250   // N/16 encoder sections
#define NH_BLOCKS 3125    // ceil(N/32) node-head sections

typedef __attribute__((ext_vector_type(8))) _Float16 f16x8;
typedef __attribute__((ext_vector_type(4))) float f32x4;

// ---------------- fused build + misc kernel ----------------
// sections: [0,HGRID) hist; [HGRID,HGRID+4) prepack_W; HGRID+4 zero pad rows;
// [HGRID+5, ...) graph_bounds.
__global__ void hist1_misc(const int* __restrict__ col, int* __restrict__ ghistT, int E,
                           const float* __restrict__ convW, uint4* __restrict__ wfrag,
                           __half* __restrict__ ht1, __half* __restrict__ ht2,
                           const int* __restrict__ batch, int* __restrict__ start) {
    __shared__ int lh[NBUK];
    int tid = threadIdx.x, b = blockIdx.x;
    if (b < HGRID) {
        for (int i = tid; i < NBUK; i += 256) lh[i] = 0;
        __syncthreads();
        for (int e = b * 256 + tid; e < E; e += HGRID * 256) atomicAdd(&lh[col[e] >> 7], 1);
        __syncthreads();
        for (int i = tid; i < NBUK; i += 256) ghistT[i * 256 + b] = lh[i];
    } else if (b < HGRID + 4) {
        int layer = b - HGRID;
        const float* W = convW + (size_t)layer * HD * HD;
        uint4* out = wfrag + (size_t)layer * 512;
        for (int s = tid; s < 512; s += 256) {
            int jt = s >> 7, ks = (s >> 6) & 1, l = s & 63;
            int j = jt * 16 + (l & 15);
            int k0 = ks * 32 + (l >> 4) * 8;
            __align__(16) __half hh[8];
            #pragma unroll
            for (int i = 0; i < 8; ++i) hh[i] = __float2half_rn(W[(size_t)(k0 + i) * HD + j]);
            out[s] = *reinterpret_cast<const uint4*>(hh);
        }
    } else if (b == HGRID + 4) {
        if (tid < HD) ht1[(size_t)N_NODES * HD + tid] = __float2half_rn(0.f);
        else if (tid < 2 * HD) ht2[(size_t)N_NODES * HD + (tid - HD)] = __float2half_rn(0.f);
    } else {
        int i = (b - HGRID - 5) * 256 + tid;
        if (i < N_NODES) {
            int bb = batch[i];
            if (i == 0) {
                for (int g = 0; g <= bb; ++g) start[g] = 0;
            } else {
                int pb = batch[i - 1];
                if (pb != bb) for (int g = pb + 1; g <= bb; ++g) start[g] = i;
            }
            if (i == N_NODES - 1) {
                for (int g = bb + 1; g <= N_GRAPHS; ++g) start[g] = N_NODES;
            }
        }
    }
}

// per-bucket exclusive scan over the 256 block counts; tot[k] = bucket total
__global__ void hist_colscan(int* __restrict__ ghistT, int* __restrict__ tot) {
    __shared__ int wsum[4];
    int k = blockIdx.x, tid = threadIdx.x;
    int v = ghistT[k * 256 + tid];
    int incl = v;
    int lane = tid & 63;
    #pragma unroll
    for (int off = 1; off < 64; off <<= 1) {
        int t = __shfl_up(incl, (unsigned)off, 64);
        if (lane >= off) incl += t;
    }
    if (lane == 63) wsum[tid >> 6] = incl;
    __syncthreads();
    int woff = 0;
    for (int w = 0; w < (tid >> 6); ++w) woff += wsum[w];
    ghistT[k * 256 + tid] = woff + incl - v;  // exclusive
    if (tid == 255) tot[k] = woff + incl;
}

// generic 1-block exclusive scan (up to 1024 elems)
__global__ void scan1(const int* __restrict__ in, int* __restrict__ out,
                      int* __restrict__ bsums, int n) {
    __shared__ int wsum[4];
    int tid = threadIdx.x;
    int base = blockIdx.x * 1024 + tid * 4;
    int v0 = (base + 0 < n) ? in[base + 0] : 0;
    int v1 = (base + 1 < n) ? in[base + 1] : 0;
    int v2 = (base + 2 < n) ? in[base + 2] : 0;
    int v3 = (base + 3 < n) ? in[base + 3] : 0;
    int tsum = v0 + v1 + v2 + v3;
    int incl = tsum;
    int lane = tid & 63;
    #pragma unroll
    for (int off = 1; off < 64; off <<= 1) {
        int t = __shfl_up(incl, (unsigned)off, 64);
        if (lane >= off) incl += t;
    }
    if (lane == 63) wsum[tid >> 6] = incl;
    __syncthreads();
    int woff = 0;
    for (int w = 0; w < (tid >> 6); ++w) woff += wsum[w];
    int run = woff + incl - tsum;
    if (base + 0 < n) out[base + 0] = run; run += v0;
    if (base + 1 < n) out[base + 1] = run; run += v1;
    if (base + 2 < n) out[base + 2] = run; run += v2;
    if (base + 3 < n) out[base + 3] = run;
    if (tid == 255) bsums[blockIdx.x] = woff + incl;
}

// scatter edges into bucket segments (LDS cursors, packed row|local<<25)
__global__ void scatter_buckets(const int* __restrict__ row, const int* __restrict__ col,
                                const int* __restrict__ ghistT, const int* __restrict__ boff,
                                unsigned* __restrict__ bke, int E) {
    __shared__ int cur[NBUK];
    int tid = threadIdx.x, b = blockIdx.x;
    for (int i = tid; i < NBUK; i += 256) cur[i] = ghistT[i * 256 + b] + boff[i];
    __syncthreads();
    for (int e = b * 256 + tid; e < E; e += HGRID * 256) {
        int c = col[e];
        int pos = atomicAdd(&cur[c >> 7], 1);  // LDS atomic
        bke[pos] = (unsigned)row[e] | ((unsigned)(c & 127) << 25);
    }
}

// per-bucket LDS count per (node, chunk) -> cnt4c (padded to 4), dis, btot
__global__ void bucket_count(const unsigned* __restrict__ bke, const int* __restrict__ boff,
                             int* __restrict__ cnt4c, float* __restrict__ dis,
                             int* __restrict__ btot, int E) {
    __shared__ int lc[128 * NC];
    __shared__ int red[4];
    int k = blockIdx.x, tid = threadIdx.x;
    for (int i = tid; i < 128 * NC; i += 256) lc[i] = 0;
    __syncthreads();
    int s = boff[k];
    int t = (k == NBUK - 1) ? E : boff[k + 1];
    for (int i = s + tid; i < t; i += 256) {
        unsigned u = bke[i];
        int l = u >> 25;
        unsigned src = u & 0x01FFFFFFu;
        atomicAdd(&lc[l * NC + (int)(src / CHUNK_SZ)], 1);  // LDS atomic
    }
    __syncthreads();
    int padsum = 0;
    for (int i = tid; i < 128 * NC; i += 256) {  // i = l*NC + c
        int p4 = (lc[i] + 3) & ~3;
        int node = k * 128 + (i >> 2);
        cnt4c[(size_t)node * NC + (i & 3)] = p4;  // node < N_CAP always
        padsum += p4;
    }
    if (tid < 128) {
        int node = k * 128 + tid;
        if (node < N_NODES) {
            int deg = lc[tid * NC] + lc[tid * NC + 1] + lc[tid * NC + 2] + lc[tid * NC + 3];
            dis[node] = rsqrtf((float)(deg + 1));
        }
    }
    int lane = tid & 63;
    #pragma unroll
    for (int off = 1; off < 64; off <<= 1) padsum += __shfl_xor(padsum, off, 64);
    if (lane == 0) red[tid >> 6] = padsum;
    __syncthreads();
    if (tid == 0) btot[k] = red[0] + red[1] + red[2] + red[3];
}

// fused: per-bucket CSR fill in (half, chunk, dest) order (+segoff table, +pads)
// AND encoder sections. Order index within bucket: oi = (l>>6)*256 + c*64 + (l&63).
__global__ void fill_enc(const unsigned* __restrict__ bke, const int* __restrict__ boff,
                         const int* __restrict__ bbase, const int* __restrict__ cnt4c,
                         int* __restrict__ segoff, int* __restrict__ srcs, int E,
                         const float* __restrict__ x, const float* __restrict__ encW,
                         const float* __restrict__ encb, const float* __restrict__ dis,
                         __half* __restrict__ ht) {
    __shared__ int segL[512];
    __shared__ int curO[512];
    __shared__ int wsum[4];
    __shared__ float Ws[F_INN * HD];
    __shared__ float bs[HD];
    __shared__ float xs[16 * F_INN];
    int tid = threadIdx.x;
    int b = blockIdx.x;
    if (b < NBUK) {
        int k = b;
        // padded counts for this thread's 2 order-slots
        int e0 = tid * 2, e1 = tid * 2 + 1;
        auto padof = [&](int e) -> int {
            int l = ((e >> 8) << 6) | (e & 63);
            int c = (e >> 6) & 3;
            return cnt4c[(size_t)(k * 128 + l) * NC + c];
        };
        int v0 = padof(e0), v1 = padof(e1);
        int tsum = v0 + v1;
        int incl = tsum;
        int lane = tid & 63;
        #pragma unroll
        for (int off = 1; off < 64; off <<= 1) {
            int t = __shfl_up(incl, (unsigned)off, 64);
            if (lane >= off) incl += t;
        }
        if (lane == 63) wsum[tid >> 6] = incl;
        __syncthreads();
        int woff = 0;
        for (int w = 0; w < (tid >> 6); ++w) woff += wsum[w];
        int base = bbase[k] + woff + incl - tsum;
        segL[e0] = base;
        segL[e1] = base + v0;
        curO[e0] = 0;
        curO[e1] = 0;
        // write global segoff table
        {
            int l0 = ((e0 >> 8) << 6) | (e0 & 63), c0 = (e0 >> 6) & 3;
            int l1 = ((e1 >> 8) << 6) | (e1 & 63), c1 = (e1 >> 6) & 3;
            segoff[(size_t)(k * 128 + l0) * NC + c0] = base;
            segoff[(size_t)(k * 128 + l1) * NC + c1] = base + v0;
        }
        __syncthreads();
        int s = boff[k];
        int t = (k == NBUK - 1) ? E : boff[k + 1];
        for (int i = s + tid; i < t; i += 256) {
            unsigned u = bke[i];
            int l = u >> 25;
            unsigned src = u & 0x01FFFFFFu;
            int c = (int)(src / CHUNK_SZ);
            int oi = ((l >> 6) << 8) | (c << 6) | (l & 63);
            int r = atomicAdd(&curO[oi], 1);  // LDS atomic
            srcs[segL[oi] + r] = (int)src;
        }
        __syncthreads();
        // pads -> zero row
        {
            int raw0 = curO[e0], st0 = segL[e0];
            for (int p = st0 + raw0; p < st0 + v0; ++p) srcs[p] = N_NODES;
            int raw1 = curO[e1], st1 = segL[e1];
            for (int p = st1 + raw1; p < st1 + v1; ++p) srcs[p] = N_NODES;
        }
    } else {
        // encoder: ht = fp16( dis * relu(x @ encW + encb) )
        for (int i = tid; i < F_INN * HD; i += 256) Ws[i] = encW[i];
        if (tid < HD) bs[tid] = encb[tid];
        int n0 = (b - NBUK) * 16;
        for (int i = tid; i < 16 * F_INN; i += 256) {
            int nn = n0 + i / F_INN;
            xs[i] = (nn < N_NODES) ? x[(size_t)nn * F_INN + (i % F_INN)] : 0.f;
        }
        __syncthreads();
        #pragma unroll
        for (int it = 0; it < 4; ++it) {
            int l = it * 4 + (tid >> 6);
            int j = tid & 63;
            int nn = n0 + l;
            if (nn < N_NODES) {
                float a = bs[j];
                #pragma unroll
                for (int k = 0; k < F_INN; ++k) a = fmaf(xs[l * F_INN + k], Ws[k * HD + j], a);
                ht[(size_t)nn * HD + j] = __float2half_rn(dis[nn] * fmaxf(a, 0.f));
            }
        }
    }
}

// ---------------- GCN layer ----------------

__device__ __forceinline__ float4 cvtrow(uint2 u) {
    float2 a = __half22float2(*reinterpret_cast<const __half2*>(&u.x));
    float2 b = __half22float2(*reinterpret_cast<const __half2*>(&u.y));
    return make_float4(a.x, a.y, b.x, b.y);
}

#define ROW16(src) (*reinterpret_cast<const uint2*>(&ht[(size_t)(src) * HD + fh]))
#define H2(u) (*reinterpret_cast<const __half2*>(&(u)))
// 4-row fp16 tree -> fp32 accumulate
#define ACC4T(r0, r1, r2, r3) { \
    __half2 ax = __hadd2(__hadd2(H2(r0.x), H2(r1.x)), __hadd2(H2(r2.x), H2(r3.x))); \
    __half2 ay = __hadd2(__hadd2(H2(r0.y), H2(r1.y)), __hadd2(H2(r2.y), H2(r3.y))); \
    float2 fx = __half22float2(ax); \
    float2 fy = __half22float2(ay); \
    acc.x += fx.x; acc.y += fx.y; acc.z += fy.x; acc.w += fy.y; }

// Source-chunked bucketed GCN layer: block owns 64 dests; CSR ordered
// (chunk, dest) within block, per-(dest,chunk) segments padded to 4 slots.
// Quarter-wave walks its 4 dests chunk-major (all CUs read the same 3.2MB
// source window per chunk-pass -> L2-resident). Partials accumulate in fp32
// aggS via RMW at segment boundaries. Self rows pre-staged. MFMA: A from
// fp32 aggS (cvt at read), B-fragments direct from global (L2-hot).
__global__ __launch_bounds__(256, 8)
void layer_kernel(const __half* __restrict__ ht,
                  const int* __restrict__ segoff, const int* __restrict__ cnt4c,
                  const int4* __restrict__ srcs4,
                  const float* __restrict__ dis,
                  const uint4* __restrict__ wfragL, const float* __restrict__ bias,
                  __half* __restrict__ hout, int scaleOut) {
    __shared__ float aggS[64 * 68];  // fp32 agg rows, stride 68 floats
    __shared__ int segS[256];        // [local][c] absolute segment starts
    __shared__ int cntS[256];        // [local][c] padded counts
    __shared__ float disS[64];
    int tid = threadIdx.x;
    int b = blockIdx.x;
    segS[tid] = segoff[(size_t)b * 256 + tid];
    cntS[tid] = cnt4c[(size_t)b * 256 + tid];
    if (tid < 64) {
        int d = b * 64 + tid;
        disS[tid] = (d < N_NODES) ? dis[d] : 0.f;
    }
    __syncthreads();

    int wave = tid >> 6;
    int lane = tid & 63;
    int q = lane >> 4;
    int fh = (lane & 15) * 4;  // feature offset (halfs/floats)

    int l0 = wave * 16 + q * 4;
    // pre-stage self rows (fp32) into this quarter's agg rows
    {
        int nbase = b * 64 + l0;
        #pragma unroll
        for (int d = 0; d < 4; ++d) {
            float4 sf = cvtrow(ROW16(min(nbase + d, N_NODES)));
            *reinterpret_cast<float4*>(&aggS[(l0 + d) * 68 + fh]) = sf;
        }
    }
    // chunk-major walk
    #pragma unroll 1
    for (int c = 0; c < NC; ++c) {
        int dcur = l0;
        int p = segS[l0 * 4 + c];
        int pe = segS[(l0 + 3) * 4 + c] + cntS[(l0 + 3) * 4 + c];
        int nb = p + cntS[l0 * 4 + c];
        float4 acc = {0.f, 0.f, 0.f, 0.f};
        for (; p < pe; p += 4) {
            while (p >= nb) {  // finished (dcur, c) segment -> RMW into aggS
                float4 cvv = *reinterpret_cast<float4*>(&aggS[dcur * 68 + fh]);
                cvv.x += acc.x; cvv.y += acc.y; cvv.z += acc.z; cvv.w += acc.w;
                *reinterpret_cast<float4*>(&aggS[dcur * 68 + fh]) = cvv;
                acc = make_float4(0.f, 0.f, 0.f, 0.f);
                ++dcur;
                nb = segS[dcur * 4 + c] + cntS[dcur * 4 + c];
            }
            int4 e0 = srcs4[p >> 2];
            uint2 r0 = ROW16(e0.x), r1 = ROW16(e0.y), r2 = ROW16(e0.z), r3 = ROW16(e0.w);
            ACC4T(r0, r1, r2, r3);
        }
        while (dcur <= l0 + 3) {  // trailing flushes (incl empty segments)
            float4 cvv = *reinterpret_cast<float4*>(&aggS[dcur * 68 + fh]);
            cvv.x += acc.x; cvv.y += acc.y; cvv.z += acc.z; cvv.w += acc.w;
            *reinterpret_cast<float4*>(&aggS[dcur * 68 + fh]) = cvv;
            acc = make_float4(0.f, 0.f, 0.f, 0.f);
            ++dcur;
        }
    }
    __syncthreads();

    // MFMA: wave = j-tile; A row = nt*16 + (lane&15), k = ks*32 + (lane>>4)*8 + i
    union AU { f16x8 v; __half2 h[4]; };
    f32x4 c0 = {0.f, 0.f, 0.f, 0.f}, c1 = c0, c2 = c0, c3 = c0;
    #pragma unroll
    for (int ks = 0; ks < 2; ++ks) {
        f16x8 bf = *reinterpret_cast<const f16x8*>(&wfragL[(wave * 2 + ks) * 64 + lane]);
        #pragma unroll
        for (int nt = 0; nt < 4; ++nt) {
            const float* ap = &aggS[(nt * 16 + (lane & 15)) * 68 + ks * 32 + (lane >> 4) * 8];
            float4 f0 = *reinterpret_cast<const float4*>(ap);
            float4 f1 = *reinterpret_cast<const float4*>(ap + 4);
            AU u;
            u.h[0] = __floats2half2_rn(f0.x, f0.y);
            u.h[1] = __floats2half2_rn(f0.z, f0.w);
            u.h[2] = __floats2half2_rn(f1.x, f1.y);
            u.h[3] = __floats2half2_rn(f1.z, f1.w);
            if (nt == 0) c0 = __builtin_amdgcn_mfma_f32_16x16x32_f16(u.v, bf, c0, 0, 0, 0);
            else if (nt == 1) c1 = __builtin_amdgcn_mfma_f32_16x16x32_f16(u.v, bf, c1, 0, 0, 0);
            else if (nt == 2) c2 = __builtin_amdgcn_mfma_f32_16x16x32_f16(u.v, bf, c2, 0, 0, 0);
            else c3 = __builtin_amdgcn_mfma_f32_16x16x32_f16(u.v, bf, c3, 0, 0, 0);
        }
    }
    int j = wave * 16 + (lane & 15);
    float bj = bias[j];
    #pragma unroll
    for (int nt = 0; nt < 4; ++nt) {
        f32x4 c = (nt == 0) ? c0 : (nt == 1) ? c1 : (nt == 2) ? c2 : c3;
        #pragma unroll
        for (int i = 0; i < 4; ++i) {
            int rl = nt * 16 + (lane >> 4) * 4 + i;
            int node = b * 64 + rl;
            if (node < N_NODES) {
                float dn = disS[rl];
                float o = fmaxf(fmaf(dn, c[i], bj), 0.f);
                if (scaleOut) o *= dn;
                hout[(size_t)node * HD + j] = __float2half_rn(o);
            }
        }
    }
}

// fused heads: sections [0,NH_BLOCKS) node head; rest pool quarters
__global__ void heads_kernel(const __half* __restrict__ h, const float* __restrict__ W,
                             const float* __restrict__ bb, float* __restrict__ out,
                             const int* __restrict__ start, float* __restrict__ gpart) {
    int tid = threadIdx.x;
    int b = blockIdx.x;
    if (b < NH_BLOCKS) {
        __shared__ float Ws[HD * NT];
        __shared__ float bs[NT];
        __shared__ float hs[32 * 65];
        for (int i = tid; i < HD * NT; i += 256) Ws[i] = W[i];
        if (tid < NT) bs[tid] = bb[tid];
        int n0 = b * 32;
        const unsigned* hrow = reinterpret_cast<const unsigned*>(&h[(size_t)n0 * HD]);
        for (int i = tid; i < 32 * HD / 2; i += 256) {
            unsigned u = hrow[i];
            float2 f = __half22float2(*reinterpret_cast<const __half2*>(&u));
            int el = i * 2;
            int row = el >> 6, colc = el & 63;
            hs[row * 65 + colc] = f.x;
            hs[row * 65 + colc + 1] = f.y;
        }
        __syncthreads();
        int l = tid >> 3, t = tid & 7;
        int nn = n0 + l;
        if (nn < N_NODES && t < NT) {
            float a = bs[t];
            #pragma unroll
            for (int k = 0; k < HD; ++k) a = fmaf(hs[l * 65 + k], Ws[k * NT + t], a);
            out[(size_t)nn * NT + t] = a;
        }
    } else {
        __shared__ float red[4][HD];
        int pb = b - NH_BLOCKS;
        int g = pb >> 2, q = pb & 3;
        int s0 = start[g], e0 = start[g + 1];
        int len = e0 - s0;
        int qs = s0 + (len * q) / 4;
        int qe = s0 + (len * (q + 1)) / 4;
        int wave = tid >> 6, lane = tid & 63;
        float acc = 0.f;
        for (int r = qs + wave; r < qe; r += 4) acc += __half2float(h[(size_t)r * HD + lane]);
        red[wave][lane] = acc;
        __syncthreads();
        if (wave == 0)
            gpart[(size_t)pb * HD + lane] =
                red[0][lane] + red[1][lane] + red[2][lane] + red[3][lane];
    }
}

__global__ void global_head(const float* __restrict__ gpart, const int* __restrict__ start,
                            const float* __restrict__ g1W, const float* __restrict__ g1b,
                            const float* __restrict__ g2W, const float* __restrict__ g2b,
                            float* __restrict__ out) {
    __shared__ float rS[HD];
    int g = blockIdx.x;
    int j = threadIdx.x;  // 64
    int cnt = start[g + 1] - start[g];
    float inv = 1.f / fmaxf((float)cnt, 1.f);
    rS[j] = (gpart[(size_t)(4 * g + 0) * HD + j] + gpart[(size_t)(4 * g + 1) * HD + j] +
             gpart[(size_t)(4 * g + 2) * HD + j] + gpart[(size_t)(4 * g + 3) * HD + j]) * inv;
    __syncthreads();
    float a = g1b[j];
    #pragma unroll
    for (int k = 0; k < HD; ++k) a = fmaf(rS[k], g1W[k * HD + j], a);
    a = fmaxf(a, 0.f);
    float o0 = a * g2W[j * GT + 0];
    float o1 = a * g2W[j * GT + 1];
    float o2 = a * g2W[j * GT + 2];
    float o3 = a * g2W[j * GT + 3];
    #pragma unroll
    for (int off = 1; off < 64; off <<= 1) {
        o0 += __shfl_xor(o0, off, 64);
        o1 += __shfl_xor(o1, off, 64);
        o2 += __shfl_xor(o2, off, 64);
        o3 += __shfl_xor(o3, off, 64);
    }
    if (j == 0) {
        out[g * GT + 0] = o0 + g2b[0];
        out[g * GT + 1] = o1 + g2b[1];
        out[g * GT + 2] = o2 + g2b[2];
        out[g * GT + 3] = o3 + g2b[3];
    }
}

// ---------------- launch ----------------

extern "C" void kernel_launch(void* const* d_in, const int* in_sizes, int n_in,
                              void* d_out, int out_size, void* d_ws, size_t ws_size,
                              hipStream_t stream) {
    const float* x    = (const float*)d_in[0];
    const int*   ei   = (const int*)d_in[1];
    const int*   batch= (const int*)d_in[2];
    const float* encW = (const float*)d_in[3];
    const float* encb = (const float*)d_in[4];
    const float* convW= (const float*)d_in[5];
    const float* convb= (const float*)d_in[6];
    const float* nodeW= (const float*)d_in[7];
    const float* nodeb= (const float*)d_in[8];
    const float* g1W  = (const float*)d_in[9];
    const float* g1b  = (const float*)d_in[10];
    const float* g2W  = (const float*)d_in[11];
    const float* g2b  = (const float*)d_in[12];
    float* out = (float*)d_out;

    const int N = N_NODES, E = N_EDGES;

    char* ws = (char*)d_ws;
    size_t off = 0;
    auto alloc = [&](size_t bytes) -> void* {
        void* p = ws + off;
        off += (bytes + 255) & ~(size_t)255;
        return p;
    };
    // all buffers fully written before read — no memset needed
    int*    ghistT = (int*)alloc((size_t)NBUK * 256 * 4);
    int*    tot    = (int*)alloc((size_t)NBUK * 4);
    int*    boff   = (int*)alloc((size_t)NBUK * 4);
    int*    btot   = (int*)alloc((size_t)NBUK * 4);
    int*    bbase  = (int*)alloc((size_t)NBUK * 4);
    unsigned* bke  = (unsigned*)alloc((size_t)E * 4);
    int*    cnt4c  = (int*)alloc((size_t)N_CAP * NC * 4);
    int*    segoff = (int*)alloc((size_t)N_CAP * NC * 4);
    float*  dis    = (float*)alloc((size_t)N * 4);
    int*    bsums  = (int*)alloc(256 * 4);
    int*    start  = (int*)alloc((size_t)(N_GRAPHS + 1) * 4);
    float*  gpart  = (float*)alloc((size_t)N_GRAPHS * 4 * HD * 4);
    uint4*  wfrag  = (uint4*)alloc((size_t)NLAYERS * 512 * 16);
    int*    srcs   = (int*)alloc((size_t)RECS_CAP * 4);
    __half* ht1    = (__half*)alloc((size_t)(N + 1) * HD * 2);  // +1 pad row
    __half* ht2    = (__half*)alloc((size_t)(N + 1) * HD * 2);

    // fused build + misc (hist, prepack, pad rows, graph bounds)
    hist1_misc<<<HGRID + 5 + GB_BLOCKS, 256, 0, stream>>>(ei + E, ghistT, E, convW, wfrag,
                                                          ht1, ht2, batch, start);
    hist_colscan<<<NBUK, 256, 0, stream>>>(ghistT, tot);
    scan1<<<1, 256, 0, stream>>>(tot, boff, bsums, NBUK);
    scatter_buckets<<<HGRID, 256, 0, stream>>>(ei, ei + E, ghistT, boff, bke, E);
    bucket_count<<<NBUK, 256, 0, stream>>>(bke, boff, cnt4c, dis, btot, E);
    scan1<<<1, 256, 0, stream>>>(btot, bbase, bsums, NBUK);
    fill_enc<<<NBUK + ENC_BLOCKS, 256, 0, stream>>>(bke, boff, bbase, cnt4c, segoff, srcs, E,
                                                    x, encW, encb, dis, ht1);

    __half* hin = ht1;
    __half* hot = ht2;
    for (int i = 0; i < NLAYERS; ++i) {
        layer_kernel<<<NBLK, 256, 0, stream>>>(hin, segoff, cnt4c, (const int4*)srcs, dis,
                                               wfrag + (size_t)i * 512,
                                               convb + (size_t)i * HD,
                                               hot, (i < NLAYERS - 1) ? 1 : 0);
        __half* t = hin; hin = hot; hot = t;
    }

    heads_kernel<<<NH_BLOCKS + N_GRAPHS * 4, 256, 0, stream>>>(hin, nodeW, nodeb, out,
                                                               start, gpart);
    global_head<<<N_GRAPHS, 64, 0, stream>>>(gpart, start, g1W, g1b, g2W, g2b, out + (size_t)N * NT);
}

// Round 15
// 234.072 us; speedup vs baseline: 1.0609x; 1.0609x over previous
//
#include <hip/hip_runtime.h>
#include <hip/hip_fp16.h>

#define N_NODES 100000
#define N_EDGES 1250000
#define N_GRAPHS 64
#define F_INN 29
#define HD 64
#define NT 6
#define GT 4
#define NLAYERS 4
#define RECS_CAP 3000000  // >= E + 15*N worst-case padded size
#define NBLK 1563         // ceil(N_NODES / 64) dest-buckets (layer)
#define NBUK 782          // ceil(N_NODES / 128) CSR-build buckets
#define HGRID 256         // blocks in hist/scatter (edge partition)
#define GB_BLOCKS 391     // ceil(N/256) graph_bounds sections
#define ENC_BLOCKS 6250   // N/16 encoder sections
#define NH_BLOCKS 3125    // ceil(N/32) node-head sections

typedef __attribute__((ext_vector_type(8))) _Float16 f16x8;
typedef __attribute__((ext_vector_type(4))) float f32x4;

// ---------------- fused build + misc kernel ----------------
// sections: [0,HGRID) hist; [HGRID,HGRID+4) prepack_W; HGRID+4 zero pad rows;
// [HGRID+5, HGRID+5+GB_BLOCKS) graph_bounds.
__global__ void hist1_misc(const int* __restrict__ col, int* __restrict__ ghistT, int E,
                           const float* __restrict__ convW, uint4* __restrict__ wfrag,
                           __half* __restrict__ ht1, __half* __restrict__ ht2,
                           const int* __restrict__ batch, int* __restrict__ start) {
    __shared__ int lh[NBUK];
    int tid = threadIdx.x, b = blockIdx.x;
    if (b < HGRID) {
        for (int i = tid; i < NBUK; i += 256) lh[i] = 0;
        __syncthreads();
        for (int e = b * 256 + tid; e < E; e += HGRID * 256) atomicAdd(&lh[col[e] >> 7], 1);
        __syncthreads();
        for (int i = tid; i < NBUK; i += 256) ghistT[i * 256 + b] = lh[i];
    } else if (b < HGRID + 4) {
        // prepack conv weights into MFMA B-fragment order (fp16)
        int layer = b - HGRID;
        const float* W = convW + (size_t)layer * HD * HD;
        uint4* out = wfrag + (size_t)layer * 512;
        for (int s = tid; s < 512; s += 256) {
            int jt = s >> 7, ks = (s >> 6) & 1, l = s & 63;
            int j = jt * 16 + (l & 15);
            int k0 = ks * 32 + (l >> 4) * 8;
            __align__(16) __half hh[8];
            #pragma unroll
            for (int i = 0; i < 8; ++i) hh[i] = __float2half_rn(W[(size_t)(k0 + i) * HD + j]);
            out[s] = *reinterpret_cast<const uint4*>(hh);
        }
    } else if (b == HGRID + 4) {
        if (tid < HD) ht1[(size_t)N_NODES * HD + tid] = __float2half_rn(0.f);
        else if (tid < 2 * HD) ht2[(size_t)N_NODES * HD + (tid - HD)] = __float2half_rn(0.f);
    } else {
        int i = (b - HGRID - 5) * 256 + tid;
        if (i < N_NODES) {
            int bb = batch[i];
            if (i == 0) {
                for (int g = 0; g <= bb; ++g) start[g] = 0;
            } else {
                int pb = batch[i - 1];
                if (pb != bb) for (int g = pb + 1; g <= bb; ++g) start[g] = i;
            }
            if (i == N_NODES - 1) {
                for (int g = bb + 1; g <= N_GRAPHS; ++g) start[g] = N_NODES;
            }
        }
    }
}

// per-bucket exclusive scan over the 256 block counts; tot[k] = bucket total
__global__ void hist_colscan(int* __restrict__ ghistT, int* __restrict__ tot) {
    __shared__ int wsum[4];
    int k = blockIdx.x, tid = threadIdx.x;
    int v = ghistT[k * 256 + tid];
    int incl = v;
    int lane = tid & 63;
    #pragma unroll
    for (int off = 1; off < 64; off <<= 1) {
        int t = __shfl_up(incl, (unsigned)off, 64);
        if (lane >= off) incl += t;
    }
    if (lane == 63) wsum[tid >> 6] = incl;
    __syncthreads();
    int woff = 0;
    for (int w = 0; w < (tid >> 6); ++w) woff += wsum[w];
    ghistT[k * 256 + tid] = woff + incl - v;  // exclusive
    if (tid == 255) tot[k] = woff + incl;
}

// generic 1-block exclusive scan (up to 1024 elems)
__global__ void scan1(const int* __restrict__ in, int* __restrict__ out,
                      int* __restrict__ bsums, int n) {
    __shared__ int wsum[4];
    int tid = threadIdx.x;
    int base = blockIdx.x * 1024 + tid * 4;
    int v0 = (base + 0 < n) ? in[base + 0] : 0;
    int v1 = (base + 1 < n) ? in[base + 1] : 0;
    int v2 = (base + 2 < n) ? in[base + 2] : 0;
    int v3 = (base + 3 < n) ? in[base + 3] : 0;
    int tsum = v0 + v1 + v2 + v3;
    int incl = tsum;
    int lane = tid & 63;
    #pragma unroll
    for (int off = 1; off < 64; off <<= 1) {
        int t = __shfl_up(incl, (unsigned)off, 64);
        if (lane >= off) incl += t;
    }
    if (lane == 63) wsum[tid >> 6] = incl;
    __syncthreads();
    int woff = 0;
    for (int w = 0; w < (tid >> 6); ++w) woff += wsum[w];
    int run = woff + incl - tsum;
    if (base + 0 < n) out[base + 0] = run; run += v0;
    if (base + 1 < n) out[base + 1] = run; run += v1;
    if (base + 2 < n) out[base + 2] = run; run += v2;
    if (base + 3 < n) out[base + 3] = run;
    if (tid == 255) bsums[blockIdx.x] = woff + incl;
}

__global__ void scan2(int* __restrict__ bsums, int nb) {
    __shared__ int s[256];
    int tid = threadIdx.x;
    int v = (tid < nb) ? bsums[tid] : 0;
    s[tid] = v;
    __syncthreads();
    #pragma unroll
    for (int off = 1; off < 256; off <<= 1) {
        int t = (tid >= off) ? s[tid - off] : 0;
        __syncthreads();
        s[tid] += t;
        __syncthreads();
    }
    if (tid < nb) bsums[tid] = s[tid] - v;
}

__global__ void scan3(int* __restrict__ out, const int* __restrict__ bsums, int n) {
    int i = blockIdx.x * blockDim.x + threadIdx.x;
    if (i < n) out[i] += bsums[i >> 10];
}

// scatter edges into bucket segments (LDS cursors, packed row|local<<25)
__global__ void scatter_buckets(const int* __restrict__ row, const int* __restrict__ col,
                                const int* __restrict__ ghistT, const int* __restrict__ boff,
                                unsigned* __restrict__ bke, int E) {
    __shared__ int cur[NBUK];
    int tid = threadIdx.x, b = blockIdx.x;
    for (int i = tid; i < NBUK; i += 256) cur[i] = ghistT[i * 256 + b] + boff[i];
    __syncthreads();
    for (int e = b * 256 + tid; e < E; e += HGRID * 256) {
        int c = col[e];
        int pos = atomicAdd(&cur[c >> 7], 1);  // LDS atomic
        bke[pos] = (unsigned)row[e] | ((unsigned)(c & 127) << 25);
    }
}

// per-bucket LDS count -> cnt16, dis, and bucket padded total btot[k]
__global__ void bucket_count(const unsigned* __restrict__ bke, const int* __restrict__ boff,
                             int* __restrict__ cnt16, float* __restrict__ dis,
                             int* __restrict__ btot, int E) {
    __shared__ int lc[128];
    __shared__ int red[2];
    int k = blockIdx.x, tid = threadIdx.x;
    if (tid < 128) lc[tid] = 0;
    __syncthreads();
    int s = boff[k];
    int t = (k == NBUK - 1) ? E : boff[k + 1];
    for (int i = s + tid; i < t; i += 256) atomicAdd(&lc[bke[i] >> 25], 1);  // LDS atomic
    __syncthreads();
    int c16 = 0;
    if (tid < 128) {
        int node = k * 128 + tid;
        if (node < N_NODES) {
            int c = lc[tid];
            c16 = (c + 15) & ~15;
            cnt16[node] = c16;
            dis[node] = rsqrtf((float)(c + 1));
        }
        // wave-reduce c16 over the 2 active waves
        int sum = c16;
        #pragma unroll
        for (int off = 1; off < 64; off <<= 1) sum += __shfl_xor(sum, off, 64);
        if ((tid & 63) == 0) red[tid >> 6] = sum;
    }
    __syncthreads();
    if (tid == 0) btot[k] = red[0] + red[1];
}

// fused: per-bucket CSR fill (+offs via LDS scan, +pads)  AND  encoder sections
__global__ void fill_enc(const unsigned* __restrict__ bke, const int* __restrict__ boff,
                         const int* __restrict__ bbase, const int* __restrict__ cnt16,
                         int* __restrict__ offs, int* __restrict__ srcs, int E,
                         const float* __restrict__ x, const float* __restrict__ encW,
                         const float* __restrict__ encb, const float* __restrict__ dis,
                         __half* __restrict__ ht) {
    int tid = threadIdx.x;
    int b = blockIdx.x;
    if (b < NBUK) {
        __shared__ int offsL[128];
        __shared__ int cur[128];
        __shared__ int wtot[2];
        int k = b;
        int v = 0, incl = 0;
        if (tid < 128) {
            int node = k * 128 + tid;
            v = (node < N_NODES) ? cnt16[node] : 0;
            incl = v;
            int lane = tid & 63;
            #pragma unroll
            for (int off = 1; off < 64; off <<= 1) {
                int t = __shfl_up(incl, (unsigned)off, 64);
                if (lane >= off) incl += t;
            }
            if (lane == 63) wtot[tid >> 6] = incl;
        }
        __syncthreads();
        if (tid < 128) {
            int w0 = (tid >= 64) ? wtot[0] : 0;
            int node = k * 128 + tid;
            int o = bbase[k] + w0 + incl - v;
            offsL[tid] = o;
            cur[tid] = 0;
            if (node < N_NODES) offs[node] = o;
        }
        __syncthreads();
        int s = boff[k];
        int t = (k == NBUK - 1) ? E : boff[k + 1];
        for (int i = s + tid; i < t; i += 256) {
            unsigned u = bke[i];
            int l = u >> 25;
            int r = atomicAdd(&cur[l], 1);  // LDS atomic
            srcs[offsL[l] + r] = (int)(u & 0x01FFFFFFu);
        }
        __syncthreads();
        if (tid < 128) {
            int node = k * 128 + tid;
            if (node < N_NODES) {
                int c = cur[tid];
                int c16 = (c + 15) & ~15;
                int base = offsL[tid];
                for (int p = base + c; p < base + c16; ++p) srcs[p] = N_NODES;  // pad
            }
        }
    } else {
        // encoder: ht = fp16( dis * relu(x @ encW + encb) )
        __shared__ float Ws[F_INN * HD];
        __shared__ float bs[HD];
        __shared__ float xs[16 * F_INN];
        for (int i = tid; i < F_INN * HD; i += 256) Ws[i] = encW[i];
        if (tid < HD) bs[tid] = encb[tid];
        int n0 = (b - NBUK) * 16;
        for (int i = tid; i < 16 * F_INN; i += 256) {
            int nn = n0 + i / F_INN;
            xs[i] = (nn < N_NODES) ? x[(size_t)nn * F_INN + (i % F_INN)] : 0.f;
        }
        __syncthreads();
        #pragma unroll
        for (int it = 0; it < 4; ++it) {
            int l = it * 4 + (tid >> 6);
            int j = tid & 63;
            int nn = n0 + l;
            if (nn < N_NODES) {
                float a = bs[j];
                #pragma unroll
                for (int k = 0; k < F_INN; ++k) a = fmaf(xs[l * F_INN + k], Ws[k * HD + j], a);
                ht[(size_t)nn * HD + j] = __float2half_rn(dis[nn] * fmaxf(a, 0.f));
            }
        }
    }
}

// ---------------- GCN layer ----------------

__device__ __forceinline__ float4 cvtrow(uint2 u) {
    float2 a = __half22float2(*reinterpret_cast<const __half2*>(&u.x));
    float2 b = __half22float2(*reinterpret_cast<const __half2*>(&u.y));
    return make_float4(a.x, a.y, b.x, b.y);
}

#define ROW16(src) (*reinterpret_cast<const uint2*>(&ht[(size_t)(src) * HD + fh]))
#define H2(u) (*reinterpret_cast<const __half2*>(&(u)))
// 4-row fp16 tree -> fp32 accumulate
#define ACC4T(r0, r1, r2, r3) { \
    __half2 ax = __hadd2(__hadd2(H2(r0.x), H2(r1.x)), __hadd2(H2(r2.x), H2(r3.x))); \
    __half2 ay = __hadd2(__hadd2(H2(r0.y), H2(r1.y)), __hadd2(H2(r2.y), H2(r3.y))); \
    float2 fx = __half22float2(ax); \
    float2 fy = __half22float2(ay); \
    acc.x += fx.x; acc.y += fx.y; acc.z += fy.x; acc.w += fy.y; }

// Bucketed GCN layer: block owns 64 dests; quarter-wave walks 4 dests' padded CSR
// slots (16/group, 16 rows in flight). Self rows pre-staged into aggS (latency
// hidden under gather); flush adds acc to the staged self row in fp32, stores
// fp16. Block-coop MFMA: wave = j-tile, 4 node-tiles x 2 k-steps.
__global__ void layer_kernel(const __half* __restrict__ ht,
                             const int* __restrict__ offs, const int* __restrict__ cnt16,
                             const int4* __restrict__ srcs4,
                             const float* __restrict__ dis,
                             const uint4* __restrict__ wfragL, const float* __restrict__ bias,
                             __half* __restrict__ hout, int scaleOut) {
    __shared__ uint4 WfS[512];        // 8KB B-fragments
    __shared__ __half aggS[64 * 72];  // 64 agg rows, stride 72 halfs
    __shared__ int offsS[64];
    __shared__ int cntS[64];
    __shared__ float disS[64];
    int tid = threadIdx.x;
    int b = blockIdx.x;
    WfS[tid] = wfragL[tid];
    WfS[tid + 256] = wfragL[tid + 256];
    if (tid < 64) {
        int d = b * 64 + tid;
        if (d < N_NODES) {
            offsS[tid] = offs[d];
            cntS[tid] = cnt16[d];
            disS[tid] = dis[d];
        } else {
            offsS[tid] = offs[N_NODES - 1] + cnt16[N_NODES - 1];
            cntS[tid] = 0;
            disS[tid] = 0.f;
        }
    }
    __syncthreads();

    int wave = tid >> 6;
    int lane = tid & 63;
    int q = lane >> 4;
    int fh = (lane & 15) * 4;

    int l0 = wave * 16 + q * 4;
    // pre-stage self rows into this quarter's aggS rows (global latency hidden)
    {
        int nbase = b * 64 + l0;
        *reinterpret_cast<uint2*>(&aggS[(l0 + 0) * 72 + fh]) = ROW16(min(nbase + 0, N_NODES));
        *reinterpret_cast<uint2*>(&aggS[(l0 + 1) * 72 + fh]) = ROW16(min(nbase + 1, N_NODES));
        *reinterpret_cast<uint2*>(&aggS[(l0 + 2) * 72 + fh]) = ROW16(min(nbase + 2, N_NODES));
        *reinterpret_cast<uint2*>(&aggS[(l0 + 3) * 72 + fh]) = ROW16(min(nbase + 3, N_NODES));
    }
    int s = offsS[l0];
    int e = offsS[l0 + 3] + cntS[l0 + 3];
    int dcur = l0;
    int nb = offsS[l0] + cntS[l0];
    float4 acc = {0.f, 0.f, 0.f, 0.f};

    // flush: add staged self row (fp32), store fp16 agg row, reset acc
    auto flush = [&](int d) {
        uint2 sv = *reinterpret_cast<uint2*>(&aggS[d * 72 + fh]);
        float4 sf = cvtrow(sv);
        acc.x += sf.x; acc.y += sf.y; acc.z += sf.z; acc.w += sf.w;
        __half2 h0 = __floats2half2_rn(acc.x, acc.y);
        __half2 h1 = __floats2half2_rn(acc.z, acc.w);
        uint2 w;
        w.x = *(unsigned*)&h0;
        w.y = *(unsigned*)&h1;
        *reinterpret_cast<uint2*>(&aggS[d * 72 + fh]) = w;
        acc = make_float4(0.f, 0.f, 0.f, 0.f);
    };

    for (int p = s; p < e; p += 16) {
        while (p >= nb) {
            flush(dcur);
            ++dcur;
            nb = offsS[dcur] + cntS[dcur];
        }
        int base = p >> 2;
        int4 e0 = srcs4[base + 0];
        int4 e1 = srcs4[base + 1];
        int4 e2 = srcs4[base + 2];
        int4 e3 = srcs4[base + 3];
        uint2 r0 = ROW16(e0.x), r1 = ROW16(e0.y), r2 = ROW16(e0.z), r3 = ROW16(e0.w);
        uint2 r4 = ROW16(e1.x), r5 = ROW16(e1.y), r6 = ROW16(e1.z), r7 = ROW16(e1.w);
        uint2 r8 = ROW16(e2.x), r9 = ROW16(e2.y), r10 = ROW16(e2.z), r11 = ROW16(e2.w);
        uint2 r12 = ROW16(e3.x), r13 = ROW16(e3.y), r14 = ROW16(e3.z), r15 = ROW16(e3.w);
        ACC4T(r0, r1, r2, r3);
        ACC4T(r4, r5, r6, r7);
        ACC4T(r8, r9, r10, r11);
        ACC4T(r12, r13, r14, r15);
    }
    while (dcur <= l0 + 3) {
        flush(dcur);
        ++dcur;
    }
    __syncthreads();

    f32x4 c0 = {0.f, 0.f, 0.f, 0.f}, c1 = c0, c2 = c0, c3 = c0;
    #pragma unroll
    for (int ks = 0; ks < 2; ++ks) {
        f16x8 bf = *reinterpret_cast<const f16x8*>(&WfS[(wave * 2 + ks) * 64 + lane]);
        f16x8 a0 = *reinterpret_cast<const f16x8*>(&aggS[(0 * 16 + (lane & 15)) * 72 + ks * 32 + (lane >> 4) * 8]);
        c0 = __builtin_amdgcn_mfma_f32_16x16x32_f16(a0, bf, c0, 0, 0, 0);
        f16x8 a1 = *reinterpret_cast<const f16x8*>(&aggS[(1 * 16 + (lane & 15)) * 72 + ks * 32 + (lane >> 4) * 8]);
        c1 = __builtin_amdgcn_mfma_f32_16x16x32_f16(a1, bf, c1, 0, 0, 0);
        f16x8 a2 = *reinterpret_cast<const f16x8*>(&aggS[(2 * 16 + (lane & 15)) * 72 + ks * 32 + (lane >> 4) * 8]);
        c2 = __builtin_amdgcn_mfma_f32_16x16x32_f16(a2, bf, c2, 0, 0, 0);
        f16x8 a3 = *reinterpret_cast<const f16x8*>(&aggS[(3 * 16 + (lane & 15)) * 72 + ks * 32 + (lane >> 4) * 8]);
        c3 = __builtin_amdgcn_mfma_f32_16x16x32_f16(a3, bf, c3, 0, 0, 0);
    }
    int j = wave * 16 + (lane & 15);
    float bj = bias[j];
    #pragma unroll
    for (int nt = 0; nt < 4; ++nt) {
        f32x4 c = (nt == 0) ? c0 : (nt == 1) ? c1 : (nt == 2) ? c2 : c3;
        #pragma unroll
        for (int i = 0; i < 4; ++i) {
            int rl = nt * 16 + (lane >> 4) * 4 + i;
            int node = b * 64 + rl;
            if (node < N_NODES) {
                float dn = disS[rl];
                float o = fmaxf(fmaf(dn, c[i], bj), 0.f);
                if (scaleOut) o *= dn;
                hout[(size_t)node * HD + j] = __float2half_rn(o);
            }
        }
    }
}

// fused heads: sections [0,NH_BLOCKS) node head; rest pool quarters
__global__ void heads_kernel(const __half* __restrict__ h, const float* __restrict__ W,
                             const float* __restrict__ bb, float* __restrict__ out,
                             const int* __restrict__ start, float* __restrict__ gpart) {
    int tid = threadIdx.x;
    int b = blockIdx.x;
    if (b < NH_BLOCKS) {
        __shared__ float Ws[HD * NT];
        __shared__ float bs[NT];
        __shared__ float hs[32 * 65];
        for (int i = tid; i < HD * NT; i += 256) Ws[i] = W[i];
        if (tid < NT) bs[tid] = bb[tid];
        int n0 = b * 32;
        const unsigned* hrow = reinterpret_cast<const unsigned*>(&h[(size_t)n0 * HD]);
        for (int i = tid; i < 32 * HD / 2; i += 256) {
            unsigned u = hrow[i];
            float2 f = __half22float2(*reinterpret_cast<const __half2*>(&u));
            int el = i * 2;
            int row = el >> 6, colc = el & 63;
            hs[row * 65 + colc] = f.x;
            hs[row * 65 + colc + 1] = f.y;
        }
        __syncthreads();
        int l = tid >> 3, t = tid & 7;
        int nn = n0 + l;
        if (nn < N_NODES && t < NT) {
            float a = bs[t];
            #pragma unroll
            for (int k = 0; k < HD; ++k) a = fmaf(hs[l * 65 + k], Ws[k * NT + t], a);
            out[(size_t)nn * NT + t] = a;
        }
    } else {
        __shared__ float red[4][HD];
        int pb = b - NH_BLOCKS;
        int g = pb >> 2, q = pb & 3;
        int s0 = start[g], e0 = start[g + 1];
        int len = e0 - s0;
        int qs = s0 + (len * q) / 4;
        int qe = s0 + (len * (q + 1)) / 4;
        int wave = tid >> 6, lane = tid & 63;
        float acc = 0.f;
        for (int r = qs + wave; r < qe; r += 4) acc += __half2float(h[(size_t)r * HD + lane]);
        red[wave][lane] = acc;
        __syncthreads();
        if (wave == 0)
            gpart[(size_t)pb * HD + lane] =
                red[0][lane] + red[1][lane] + red[2][lane] + red[3][lane];
    }
}

__global__ void global_head(const float* __restrict__ gpart, const int* __restrict__ start,
                            const float* __restrict__ g1W, const float* __restrict__ g1b,
                            const float* __restrict__ g2W, const float* __restrict__ g2b,
                            float* __restrict__ out) {
    __shared__ float rS[HD];
    int g = blockIdx.x;
    int j = threadIdx.x;  // 64
    int cnt = start[g + 1] - start[g];
    float inv = 1.f / fmaxf((float)cnt, 1.f);
    rS[j] = (gpart[(size_t)(4 * g + 0) * HD + j] + gpart[(size_t)(4 * g + 1) * HD + j] +
             gpart[(size_t)(4 * g + 2) * HD + j] + gpart[(size_t)(4 * g + 3) * HD + j]) * inv;
    __syncthreads();
    float a = g1b[j];
    #pragma unroll
    for (int k = 0; k < HD; ++k) a = fmaf(rS[k], g1W[k * HD + j], a);
    a = fmaxf(a, 0.f);
    float o0 = a * g2W[j * GT + 0];
    float o1 = a * g2W[j * GT + 1];
    float o2 = a * g2W[j * GT + 2];
    float o3 = a * g2W[j * GT + 3];
    #pragma unroll
    for (int off = 1; off < 64; off <<= 1) {
        o0 += __shfl_xor(o0, off, 64);
        o1 += __shfl_xor(o1, off, 64);
        o2 += __shfl_xor(o2, off, 64);
        o3 += __shfl_xor(o3, off, 64);
    }
    if (j == 0) {
        out[g * GT + 0] = o0 + g2b[0];
        out[g * GT + 1] = o1 + g2b[1];
        out[g * GT + 2] = o2 + g2b[2];
        out[g * GT + 3] = o3 + g2b[3];
    }
}

// ---------------- launch ----------------

extern "C" void kernel_launch(void* const* d_in, const int* in_sizes, int n_in,
                              void* d_out, int out_size, void* d_ws, size_t ws_size,
                              hipStream_t stream) {
    const float* x    = (const float*)d_in[0];
    const int*   ei   = (const int*)d_in[1];
    const int*   batch= (const int*)d_in[2];
    const float* encW = (const float*)d_in[3];
    const float* encb = (const float*)d_in[4];
    const float* convW= (const float*)d_in[5];
    const float* convb= (const float*)d_in[6];
    const float* nodeW= (const float*)d_in[7];
    const float* nodeb= (const float*)d_in[8];
    const float* g1W  = (const float*)d_in[9];
    const float* g1b  = (const float*)d_in[10];
    const float* g2W  = (const float*)d_in[11];
    const float* g2b  = (const float*)d_in[12];
    float* out = (float*)d_out;

    const int N = N_NODES, E = N_EDGES;

    char* ws = (char*)d_ws;
    size_t off = 0;
    auto alloc = [&](size_t bytes) -> void* {
        void* p = ws + off;
        off += (bytes + 255) & ~(size_t)255;
        return p;
    };
    // all buffers fully written before read — no memset needed
    int*    ghistT = (int*)alloc((size_t)NBUK * 256 * 4);
    int*    tot    = (int*)alloc((size_t)NBUK * 4);
    int*    boff   = (int*)alloc((size_t)NBUK * 4);
    int*    btot   = (int*)alloc((size_t)NBUK * 4);
    int*    bbase  = (int*)alloc((size_t)NBUK * 4);
    unsigned* bke  = (unsigned*)alloc((size_t)E * 4);
    int*    offs   = (int*)alloc((size_t)N * 4);
    int*    cnt16  = (int*)alloc((size_t)N * 4);
    float*  dis    = (float*)alloc((size_t)N * 4);
    int*    bsums  = (int*)alloc(256 * 4);
    int*    start  = (int*)alloc((size_t)(N_GRAPHS + 1) * 4);
    float*  gpart  = (float*)alloc((size_t)N_GRAPHS * 4 * HD * 4);
    uint4*  wfrag  = (uint4*)alloc((size_t)NLAYERS * 512 * 16);
    int*    srcs   = (int*)alloc((size_t)RECS_CAP * 4);
    __half* ht1    = (__half*)alloc((size_t)(N + 1) * HD * 2);  // +1 pad row
    __half* ht2    = (__half*)alloc((size_t)(N + 1) * HD * 2);

    // fused build + misc (hist, prepack, pad rows, graph bounds)
    hist1_misc<<<HGRID + 5 + GB_BLOCKS, 256, 0, stream>>>(ei + E, ghistT, E, convW, wfrag,
                                                          ht1, ht2, batch, start);
    hist_colscan<<<NBUK, 256, 0, stream>>>(ghistT, tot);
    scan1<<<1, 256, 0, stream>>>(tot, boff, bsums, NBUK);
    scatter_buckets<<<HGRID, 256, 0, stream>>>(ei, ei + E, ghistT, boff, bke, E);
    bucket_count<<<NBUK, 256, 0, stream>>>(bke, boff, cnt16, dis, btot, E);
    scan1<<<1, 256, 0, stream>>>(btot, bbase, bsums, NBUK);
    fill_enc<<<NBUK + ENC_BLOCKS, 256, 0, stream>>>(bke, boff, bbase, cnt16, offs, srcs, E,
                                                    x, encW, encb, dis, ht1);

    __half* hin = ht1;
    __half* hot = ht2;
    for (int i = 0; i < NLAYERS; ++i) {
        layer_kernel<<<NBLK, 256, 0, stream>>>(hin, offs, cnt16, (const int4*)srcs, dis,
                                               wfrag + (size_t)i * 512,
                                               convb + (size_t)i * HD,
                                               hot, (i < NLAYERS - 1) ? 1 : 0);
        __half* t = hin; hin = hot; hot = t;
    }

    heads_kernel<<<NH_BLOCKS + N_GRAPHS * 4, 256, 0, stream>>>(hin, nodeW, nodeb, out,
                                                               start, gpart);
    global_head<<<N_GRAPHS, 64, 0, stream>>>(gpart, start, g1W, g1b, g2W, g2b, out + (size_t)N * NT);
}

// Round 16
// 225.663 us; speedup vs baseline: 1.1004x; 1.0373x over previous
//
#include <hip/hip_runtime.h>
#include <hip/hip_fp16.h>

#define N_NODES 100000
#define N_EDGES 1250000
#define N_GRAPHS 64
#define F_INN 29
#define HD 64
#define NT 6
#define GT 4
#define NLAYERS 4
#define RECS_CAP 3000000  // >= E + 15*N worst-case padded size
#define NBLK 1563         // ceil(N_NODES / 64) dest-buckets (layer)
#define NBUK 782          // ceil(N_NODES / 128) CSR-build buckets
#define HGRID 256         // blocks in hist/scatter (edge partition)
#define GB_BLOCKS 391     // ceil(N/256) graph_bounds sections
#define ENC_BLOCKS 6250   // N/16 encoder sections
#define NH_BLOCKS 3125    // ceil(N/32) node-head sections

typedef __attribute__((ext_vector_type(8))) _Float16 f16x8;
typedef __attribute__((ext_vector_type(4))) float f32x4;

// ---------------- fused build + misc kernel ----------------
// sections: [0,HGRID) hist; [HGRID,HGRID+4) prepack_W; HGRID+4 zero pad rows;
// [HGRID+5, HGRID+5+GB_BLOCKS) graph_bounds.
__global__ void hist1_misc(const int* __restrict__ col, int* __restrict__ ghistT, int E,
                           const float* __restrict__ convW, uint4* __restrict__ wfrag,
                           __half* __restrict__ ht1, __half* __restrict__ ht2,
                           const int* __restrict__ batch, int* __restrict__ start) {
    __shared__ int lh[NBUK];
    int tid = threadIdx.x, b = blockIdx.x;
    if (b < HGRID) {
        for (int i = tid; i < NBUK; i += 256) lh[i] = 0;
        __syncthreads();
        for (int e = b * 256 + tid; e < E; e += HGRID * 256) atomicAdd(&lh[col[e] >> 7], 1);
        __syncthreads();
        for (int i = tid; i < NBUK; i += 256) ghistT[i * 256 + b] = lh[i];
    } else if (b < HGRID + 4) {
        // prepack conv weights into MFMA B-fragment order (fp16)
        int layer = b - HGRID;
        const float* W = convW + (size_t)layer * HD * HD;
        uint4* out = wfrag + (size_t)layer * 512;
        for (int s = tid; s < 512; s += 256) {
            int jt = s >> 7, ks = (s >> 6) & 1, l = s & 63;
            int j = jt * 16 + (l & 15);
            int k0 = ks * 32 + (l >> 4) * 8;
            __align__(16) __half hh[8];
            #pragma unroll
            for (int i = 0; i < 8; ++i) hh[i] = __float2half_rn(W[(size_t)(k0 + i) * HD + j]);
            out[s] = *reinterpret_cast<const uint4*>(hh);
        }
    } else if (b == HGRID + 4) {
        if (tid < HD) ht1[(size_t)N_NODES * HD + tid] = __float2half_rn(0.f);
        else if (tid < 2 * HD) ht2[(size_t)N_NODES * HD + (tid - HD)] = __float2half_rn(0.f);
    } else {
        int i = (b - HGRID - 5) * 256 + tid;
        if (i < N_NODES) {
            int bb = batch[i];
            if (i == 0) {
                for (int g = 0; g <= bb; ++g) start[g] = 0;
            } else {
                int pb = batch[i - 1];
                if (pb != bb) for (int g = pb + 1; g <= bb; ++g) start[g] = i;
            }
            if (i == N_NODES - 1) {
                for (int g = bb + 1; g <= N_GRAPHS; ++g) start[g] = N_NODES;
            }
        }
    }
}

// per-bucket exclusive scan over the 256 block counts; tot[k] = bucket total
__global__ void hist_colscan(int* __restrict__ ghistT, int* __restrict__ tot) {
    __shared__ int wsum[4];
    int k = blockIdx.x, tid = threadIdx.x;
    int v = ghistT[k * 256 + tid];
    int incl = v;
    int lane = tid & 63;
    #pragma unroll
    for (int off = 1; off < 64; off <<= 1) {
        int t = __shfl_up(incl, (unsigned)off, 64);
        if (lane >= off) incl += t;
    }
    if (lane == 63) wsum[tid >> 6] = incl;
    __syncthreads();
    int woff = 0;
    for (int w = 0; w < (tid >> 6); ++w) woff += wsum[w];
    ghistT[k * 256 + tid] = woff + incl - v;  // exclusive
    if (tid == 255) tot[k] = woff + incl;
}

// generic 1-block exclusive scan (up to 1024 elems)
__global__ void scan1(const int* __restrict__ in, int* __restrict__ out,
                      int* __restrict__ bsums, int n) {
    __shared__ int wsum[4];
    int tid = threadIdx.x;
    int base = blockIdx.x * 1024 + tid * 4;
    int v0 = (base + 0 < n) ? in[base + 0] : 0;
    int v1 = (base + 1 < n) ? in[base + 1] : 0;
    int v2 = (base + 2 < n) ? in[base + 2] : 0;
    int v3 = (base + 3 < n) ? in[base + 3] : 0;
    int tsum = v0 + v1 + v2 + v3;
    int incl = tsum;
    int lane = tid & 63;
    #pragma unroll
    for (int off = 1; off < 64; off <<= 1) {
        int t = __shfl_up(incl, (unsigned)off, 64);
        if (lane >= off) incl += t;
    }
    if (lane == 63) wsum[tid >> 6] = incl;
    __syncthreads();
    int woff = 0;
    for (int w = 0; w < (tid >> 6); ++w) woff += wsum[w];
    int run = woff + incl - tsum;
    if (base + 0 < n) out[base + 0] = run; run += v0;
    if (base + 1 < n) out[base + 1] = run; run += v1;
    if (base + 2 < n) out[base + 2] = run; run += v2;
    if (base + 3 < n) out[base + 3] = run;
    if (tid == 255) bsums[blockIdx.x] = woff + incl;
}

// scatter edges into bucket segments (LDS cursors, packed row|local<<25)
__global__ void scatter_buckets(const int* __restrict__ row, const int* __restrict__ col,
                                const int* __restrict__ ghistT, const int* __restrict__ boff,
                                unsigned* __restrict__ bke, int E) {
    __shared__ int cur[NBUK];
    int tid = threadIdx.x, b = blockIdx.x;
    for (int i = tid; i < NBUK; i += 256) cur[i] = ghistT[i * 256 + b] + boff[i];
    __syncthreads();
    for (int e = b * 256 + tid; e < E; e += HGRID * 256) {
        int c = col[e];
        int pos = atomicAdd(&cur[c >> 7], 1);  // LDS atomic
        bke[pos] = (unsigned)row[e] | ((unsigned)(c & 127) << 25);
    }
}

// per-bucket LDS count -> cnt16, dis, and bucket padded total btot[k]
__global__ void bucket_count(const unsigned* __restrict__ bke, const int* __restrict__ boff,
                             int* __restrict__ cnt16, float* __restrict__ dis,
                             int* __restrict__ btot, int E) {
    __shared__ int lc[128];
    __shared__ int red[2];
    int k = blockIdx.x, tid = threadIdx.x;
    if (tid < 128) lc[tid] = 0;
    __syncthreads();
    int s = boff[k];
    int t = (k == NBUK - 1) ? E : boff[k + 1];
    for (int i = s + tid; i < t; i += 256) atomicAdd(&lc[bke[i] >> 25], 1);  // LDS atomic
    __syncthreads();
    int c16 = 0;
    if (tid < 128) {
        int node = k * 128 + tid;
        if (node < N_NODES) {
            int c = lc[tid];
            c16 = (c + 15) & ~15;
            cnt16[node] = c16;
            dis[node] = rsqrtf((float)(c + 1));
        }
        // wave-reduce c16 over the 2 active waves
        int sum = c16;
        #pragma unroll
        for (int off = 1; off < 64; off <<= 1) sum += __shfl_xor(sum, off, 64);
        if ((tid & 63) == 0) red[tid >> 6] = sum;
    }
    __syncthreads();
    if (tid == 0) btot[k] = red[0] + red[1];
}

// fused: per-bucket CSR fill (+offs via LDS scan, +pads)  AND  encoder sections
__global__ void fill_enc(const unsigned* __restrict__ bke, const int* __restrict__ boff,
                         const int* __restrict__ bbase, const int* __restrict__ cnt16,
                         int* __restrict__ offs, int* __restrict__ srcs, int E,
                         const float* __restrict__ x, const float* __restrict__ encW,
                         const float* __restrict__ encb, const float* __restrict__ dis,
                         __half* __restrict__ ht) {
    int tid = threadIdx.x;
    int b = blockIdx.x;
    if (b < NBUK) {
        __shared__ int offsL[128];
        __shared__ int cur[128];
        __shared__ int wtot[2];
        int k = b;
        int v = 0, incl = 0;
        if (tid < 128) {
            int node = k * 128 + tid;
            v = (node < N_NODES) ? cnt16[node] : 0;
            incl = v;
            int lane = tid & 63;
            #pragma unroll
            for (int off = 1; off < 64; off <<= 1) {
                int t = __shfl_up(incl, (unsigned)off, 64);
                if (lane >= off) incl += t;
            }
            if (lane == 63) wtot[tid >> 6] = incl;
        }
        __syncthreads();
        if (tid < 128) {
            int w0 = (tid >= 64) ? wtot[0] : 0;
            int node = k * 128 + tid;
            int o = bbase[k] + w0 + incl - v;
            offsL[tid] = o;
            cur[tid] = 0;
            if (node < N_NODES) offs[node] = o;
        }
        __syncthreads();
        int s = boff[k];
        int t = (k == NBUK - 1) ? E : boff[k + 1];
        for (int i = s + tid; i < t; i += 256) {
            unsigned u = bke[i];
            int l = u >> 25;
            int r = atomicAdd(&cur[l], 1);  // LDS atomic
            srcs[offsL[l] + r] = (int)(u & 0x01FFFFFFu);
        }
        __syncthreads();
        if (tid < 128) {
            int node = k * 128 + tid;
            if (node < N_NODES) {
                int c = cur[tid];
                int c16 = (c + 15) & ~15;
                int base = offsL[tid];
                for (int p = base + c; p < base + c16; ++p) srcs[p] = N_NODES;  // pad
            }
        }
    } else {
        // encoder: ht = fp16( dis * relu(x @ encW + encb) )
        __shared__ float Ws[F_INN * HD];
        __shared__ float bs[HD];
        __shared__ float xs[16 * F_INN];
        for (int i = tid; i < F_INN * HD; i += 256) Ws[i] = encW[i];
        if (tid < HD) bs[tid] = encb[tid];
        int n0 = (b - NBUK) * 16;
        for (int i = tid; i < 16 * F_INN; i += 256) {
            int nn = n0 + i / F_INN;
            xs[i] = (nn < N_NODES) ? x[(size_t)nn * F_INN + (i % F_INN)] : 0.f;
        }
        __syncthreads();
        #pragma unroll
        for (int it = 0; it < 4; ++it) {
            int l = it * 4 + (tid >> 6);
            int j = tid & 63;
            int nn = n0 + l;
            if (nn < N_NODES) {
                float a = bs[j];
                #pragma unroll
                for (int k = 0; k < F_INN; ++k) a = fmaf(xs[l * F_INN + k], Ws[k * HD + j], a);
                ht[(size_t)nn * HD + j] = __float2half_rn(dis[nn] * fmaxf(a, 0.f));
            }
        }
    }
}

// ---------------- GCN layer ----------------

__device__ __forceinline__ float4 cvtrow(uint2 u) {
    float2 a = __half22float2(*reinterpret_cast<const __half2*>(&u.x));
    float2 b = __half22float2(*reinterpret_cast<const __half2*>(&u.y));
    return make_float4(a.x, a.y, b.x, b.y);
}

#define ROW16(src) (*reinterpret_cast<const uint2*>(&ht[(size_t)(src) * HD + fh]))
#define H2(u) (*reinterpret_cast<const __half2*>(&(u)))
// 4-row fp16 tree -> fp32 accumulate
#define ACC4T(r0, r1, r2, r3) { \
    __half2 ax = __hadd2(__hadd2(H2(r0.x), H2(r1.x)), __hadd2(H2(r2.x), H2(r3.x))); \
    __half2 ay = __hadd2(__hadd2(H2(r0.y), H2(r1.y)), __hadd2(H2(r2.y), H2(r3.y))); \
    float2 fx = __half22float2(ax); \
    float2 fy = __half22float2(ay); \
    acc.x += fx.x; acc.y += fx.y; acc.z += fy.x; acc.w += fy.y; }

// Bucketed GCN layer, barrier-free main path: block owns 64 dests; quarter-wave
// walks 4 dests' padded CSR slots (16/group, 16 rows in flight, next-group
// indices prefetched). Self rows pre-staged into aggS; flush adds acc in fp32,
// stores fp16. MFMA is WAVE-LOCAL: wave = node-tile (its own 16 aggS rows),
// computing all 4 j-tiles -> no gather/MFMA barrier; fast waves run ahead.
__global__ void layer_kernel(const __half* __restrict__ ht,
                             const int* __restrict__ offs, const int* __restrict__ cnt16,
                             const int4* __restrict__ srcs4,
                             const float* __restrict__ dis,
                             const uint4* __restrict__ wfragL, const float* __restrict__ bias,
                             __half* __restrict__ hout, int scaleOut) {
    __shared__ uint4 WfS[512];        // 8KB B-fragments (all j-tiles)
    __shared__ __half aggS[64 * 72];  // 64 agg rows, stride 72 halfs
    __shared__ int offsS[64];
    __shared__ int cntS[64];
    __shared__ float disS[64];
    __shared__ float biasS[64];
    int tid = threadIdx.x;
    int b = blockIdx.x;
    WfS[tid] = wfragL[tid];
    WfS[tid + 256] = wfragL[tid + 256];
    if (tid < 64) {
        int d = b * 64 + tid;
        biasS[tid] = bias[tid];
        if (d < N_NODES) {
            offsS[tid] = offs[d];
            cntS[tid] = cnt16[d];
            disS[tid] = dis[d];
        } else {
            offsS[tid] = offs[N_NODES - 1] + cnt16[N_NODES - 1];
            cntS[tid] = 0;
            disS[tid] = 0.f;
        }
    }
    __syncthreads();  // the only block barrier (staging)

    int wave = tid >> 6;
    int lane = tid & 63;
    int q = lane >> 4;
    int fh = (lane & 15) * 4;

    int l0 = wave * 16 + q * 4;
    // pre-stage self rows into this quarter's aggS rows (global latency hidden)
    {
        int nbase = b * 64 + l0;
        *reinterpret_cast<uint2*>(&aggS[(l0 + 0) * 72 + fh]) = ROW16(min(nbase + 0, N_NODES));
        *reinterpret_cast<uint2*>(&aggS[(l0 + 1) * 72 + fh]) = ROW16(min(nbase + 1, N_NODES));
        *reinterpret_cast<uint2*>(&aggS[(l0 + 2) * 72 + fh]) = ROW16(min(nbase + 2, N_NODES));
        *reinterpret_cast<uint2*>(&aggS[(l0 + 3) * 72 + fh]) = ROW16(min(nbase + 3, N_NODES));
    }
    int s = offsS[l0];
    int e = offsS[l0 + 3] + cntS[l0 + 3];
    int dcur = l0;
    int nb = offsS[l0] + cntS[l0];
    float4 acc = {0.f, 0.f, 0.f, 0.f};

    // flush: add staged self row (fp32), store fp16 agg row, reset acc
    auto flush = [&](int d) {
        uint2 sv = *reinterpret_cast<uint2*>(&aggS[d * 72 + fh]);
        float4 sf = cvtrow(sv);
        acc.x += sf.x; acc.y += sf.y; acc.z += sf.z; acc.w += sf.w;
        __half2 h0 = __floats2half2_rn(acc.x, acc.y);
        __half2 h1 = __floats2half2_rn(acc.z, acc.w);
        uint2 w;
        w.x = *(unsigned*)&h0;
        w.y = *(unsigned*)&h1;
        *reinterpret_cast<uint2*>(&aggS[d * 72 + fh]) = w;
        acc = make_float4(0.f, 0.f, 0.f, 0.f);
    };

    // software-pipelined gather: indices for group p prefetched at p-16
    int4 i0, i1, i2, i3;
    if (s < e) {
        int base = s >> 2;
        i0 = srcs4[base + 0];
        i1 = srcs4[base + 1];
        i2 = srcs4[base + 2];
        i3 = srcs4[base + 3];
    }
    for (int p = s; p < e; p += 16) {
        // issue row loads for current group (consume i0..i3)
        uint2 r0 = ROW16(i0.x), r1 = ROW16(i0.y), r2 = ROW16(i0.z), r3 = ROW16(i0.w);
        uint2 r4 = ROW16(i1.x), r5 = ROW16(i1.y), r6 = ROW16(i1.z), r7 = ROW16(i1.w);
        uint2 r8 = ROW16(i2.x), r9 = ROW16(i2.y), r10 = ROW16(i2.z), r11 = ROW16(i2.w);
        uint2 r12 = ROW16(i3.x), r13 = ROW16(i3.y), r14 = ROW16(i3.z), r15 = ROW16(i3.w);
        // prefetch next group's indices
        int pn = p + 16;
        if (pn < e) {
            int base = pn >> 2;
            i0 = srcs4[base + 0];
            i1 = srcs4[base + 1];
            i2 = srcs4[base + 2];
            i3 = srcs4[base + 3];
        }
        // flush finished dest(s) before accumulating this group
        while (p >= nb) {
            flush(dcur);
            ++dcur;
            nb = offsS[dcur] + cntS[dcur];
        }
        ACC4T(r0, r1, r2, r3);
        ACC4T(r4, r5, r6, r7);
        ACC4T(r8, r9, r10, r11);
        ACC4T(r12, r13, r14, r15);
    }
    while (dcur <= l0 + 3) {
        flush(dcur);
        ++dcur;
    }

    // WAVE-LOCAL MFMA: wave = node-tile; A row = wave*16 + (lane&15),
    // k = ks*32 + (lane>>4)*8 + i; B = j-tile jt (all 4). No barrier needed:
    // aggS rows [wave*16, wave*16+16) were written by this wave only.
    f32x4 c0 = {0.f, 0.f, 0.f, 0.f}, c1 = c0, c2 = c0, c3 = c0;
    #pragma unroll
    for (int ks = 0; ks < 2; ++ks) {
        f16x8 a = *reinterpret_cast<const f16x8*>(
            &aggS[(wave * 16 + (lane & 15)) * 72 + ks * 32 + (lane >> 4) * 8]);
        f16x8 b0 = *reinterpret_cast<const f16x8*>(&WfS[(0 * 2 + ks) * 64 + lane]);
        c0 = __builtin_amdgcn_mfma_f32_16x16x32_f16(a, b0, c0, 0, 0, 0);
        f16x8 b1 = *reinterpret_cast<const f16x8*>(&WfS[(1 * 2 + ks) * 64 + lane]);
        c1 = __builtin_amdgcn_mfma_f32_16x16x32_f16(a, b1, c1, 0, 0, 0);
        f16x8 b2 = *reinterpret_cast<const f16x8*>(&WfS[(2 * 2 + ks) * 64 + lane]);
        c2 = __builtin_amdgcn_mfma_f32_16x16x32_f16(a, b2, c2, 0, 0, 0);
        f16x8 b3 = *reinterpret_cast<const f16x8*>(&WfS[(3 * 2 + ks) * 64 + lane]);
        c3 = __builtin_amdgcn_mfma_f32_16x16x32_f16(a, b3, c3, 0, 0, 0);
    }
    // epilogue: D col = lane&15 (j within tile jt), row = (lane>>4)*4 + i (node
    // within this wave's tile)
    #pragma unroll
    for (int jt = 0; jt < 4; ++jt) {
        f32x4 c = (jt == 0) ? c0 : (jt == 1) ? c1 : (jt == 2) ? c2 : c3;
        int j = jt * 16 + (lane & 15);
        float bj = biasS[j];
        #pragma unroll
        for (int i = 0; i < 4; ++i) {
            int rl = wave * 16 + (lane >> 4) * 4 + i;
            int node = b * 64 + rl;
            if (node < N_NODES) {
                float dn = disS[rl];
                float o = fmaxf(fmaf(dn, c[i], bj), 0.f);
                if (scaleOut) o *= dn;
                hout[(size_t)node * HD + j] = __float2half_rn(o);
            }
        }
    }
}

// fused heads: sections [0,NH_BLOCKS) node head; rest pool quarters
__global__ void heads_kernel(const __half* __restrict__ h, const float* __restrict__ W,
                             const float* __restrict__ bb, float* __restrict__ out,
                             const int* __restrict__ start, float* __restrict__ gpart) {
    int tid = threadIdx.x;
    int b = blockIdx.x;
    if (b < NH_BLOCKS) {
        __shared__ float Ws[HD * NT];
        __shared__ float bs[NT];
        __shared__ float hs[32 * 65];
        for (int i = tid; i < HD * NT; i += 256) Ws[i] = W[i];
        if (tid < NT) bs[tid] = bb[tid];
        int n0 = b * 32;
        const unsigned* hrow = reinterpret_cast<const unsigned*>(&h[(size_t)n0 * HD]);
        for (int i = tid; i < 32 * HD / 2; i += 256) {
            unsigned u = hrow[i];
            float2 f = __half22float2(*reinterpret_cast<const __half2*>(&u));
            int el = i * 2;
            int row = el >> 6, colc = el & 63;
            hs[row * 65 + colc] = f.x;
            hs[row * 65 + colc + 1] = f.y;
        }
        __syncthreads();
        int l = tid >> 3, t = tid & 7;
        int nn = n0 + l;
        if (nn < N_NODES && t < NT) {
            float a = bs[t];
            #pragma unroll
            for (int k = 0; k < HD; ++k) a = fmaf(hs[l * 65 + k], Ws[k * NT + t], a);
            out[(size_t)nn * NT + t] = a;
        }
    } else {
        __shared__ float red[4][HD];
        int pb = b - NH_BLOCKS;
        int g = pb >> 2, q = pb & 3;
        int s0 = start[g], e0 = start[g + 1];
        int len = e0 - s0;
        int qs = s0 + (len * q) / 4;
        int qe = s0 + (len * (q + 1)) / 4;
        int wave = tid >> 6, lane = tid & 63;
        float acc = 0.f;
        for (int r = qs + wave; r < qe; r += 4) acc += __half2float(h[(size_t)r * HD + lane]);
        red[wave][lane] = acc;
        __syncthreads();
        if (wave == 0)
            gpart[(size_t)pb * HD + lane] =
                red[0][lane] + red[1][lane] + red[2][lane] + red[3][lane];
    }
}

__global__ void global_head(const float* __restrict__ gpart, const int* __restrict__ start,
                            const float* __restrict__ g1W, const float* __restrict__ g1b,
                            const float* __restrict__ g2W, const float* __restrict__ g2b,
                            float* __restrict__ out) {
    __shared__ float rS[HD];
    int g = blockIdx.x;
    int j = threadIdx.x;  // 64
    int cnt = start[g + 1] - start[g];
    float inv = 1.f / fmaxf((float)cnt, 1.f);
    rS[j] = (gpart[(size_t)(4 * g + 0) * HD + j] + gpart[(size_t)(4 * g + 1) * HD + j] +
             gpart[(size_t)(4 * g + 2) * HD + j] + gpart[(size_t)(4 * g + 3) * HD + j]) * inv;
    __syncthreads();
    float a = g1b[j];
    #pragma unroll
    for (int k = 0; k < HD; ++k) a = fmaf(rS[k], g1W[k * HD + j], a);
    a = fmaxf(a, 0.f);
    float o0 = a * g2W[j * GT + 0];
    float o1 = a * g2W[j * GT + 1];
    float o2 = a * g2W[j * GT + 2];
    float o3 = a * g2W[j * GT + 3];
    #pragma unroll
    for (int off = 1; off < 64; off <<= 1) {
        o0 += __shfl_xor(o0, off, 64);
        o1 += __shfl_xor(o1, off, 64);
        o2 += __shfl_xor(o2, off, 64);
        o3 += __shfl_xor(o3, off, 64);
    }
    if (j == 0) {
        out[g * GT + 0] = o0 + g2b[0];
        out[g * GT + 1] = o1 + g2b[1];
        out[g * GT + 2] = o2 + g2b[2];
        out[g * GT + 3] = o3 + g2b[3];
    }
}

// ---------------- launch ----------------

extern "C" void kernel_launch(void* const* d_in, const int* in_sizes, int n_in,
                              void* d_out, int out_size, void* d_ws, size_t ws_size,
                              hipStream_t stream) {
    const float* x    = (const float*)d_in[0];
    const int*   ei   = (const int*)d_in[1];
    const int*   batch= (const int*)d_in[2];
    const float* encW = (const float*)d_in[3];
    const float* encb = (const float*)d_in[4];
    const float* convW= (const float*)d_in[5];
    const float* convb= (const float*)d_in[6];
    const float* nodeW= (const float*)d_in[7];
    const float* nodeb= (const float*)d_in[8];
    const float* g1W  = (const float*)d_in[9];
    const float* g1b  = (const float*)d_in[10];
    const float* g2W  = (const float*)d_in[11];
    const float* g2b  = (const float*)d_in[12];
    float* out = (float*)d_out;

    const int N = N_NODES, E = N_EDGES;

    char* ws = (char*)d_ws;
    size_t off = 0;
    auto alloc = [&](size_t bytes) -> void* {
        void* p = ws + off;
        off += (bytes + 255) & ~(size_t)255;
        return p;
    };
    // all buffers fully written before read — no memset needed
    int*    ghistT = (int*)alloc((size_t)NBUK * 256 * 4);
    int*    tot    = (int*)alloc((size_t)NBUK * 4);
    int*    boff   = (int*)alloc((size_t)NBUK * 4);
    int*    btot   = (int*)alloc((size_t)NBUK * 4);
    int*    bbase  = (int*)alloc((size_t)NBUK * 4);
    unsigned* bke  = (unsigned*)alloc((size_t)E * 4);
    int*    offs   = (int*)alloc((size_t)N * 4);
    int*    cnt16  = (int*)alloc((size_t)N * 4);
    float*  dis    = (float*)alloc((size_t)N * 4);
    int*    bsums  = (int*)alloc(256 * 4);
    int*    start  = (int*)alloc((size_t)(N_GRAPHS + 1) * 4);
    float*  gpart  = (float*)alloc((size_t)N_GRAPHS * 4 * HD * 4);
    uint4*  wfrag  = (uint4*)alloc((size_t)NLAYERS * 512 * 16);
    int*    srcs   = (int*)alloc((size_t)RECS_CAP * 4);
    __half* ht1    = (__half*)alloc((size_t)(N + 1) * HD * 2);  // +1 pad row
    __half* ht2    = (__half*)alloc((size_t)(N + 1) * HD * 2);

    // fused build + misc (hist, prepack, pad rows, graph bounds)
    hist1_misc<<<HGRID + 5 + GB_BLOCKS, 256, 0, stream>>>(ei + E, ghistT, E, convW, wfrag,
                                                          ht1, ht2, batch, start);
    hist_colscan<<<NBUK, 256, 0, stream>>>(ghistT, tot);
    scan1<<<1, 256, 0, stream>>>(tot, boff, bsums, NBUK);
    scatter_buckets<<<HGRID, 256, 0, stream>>>(ei, ei + E, ghistT, boff, bke, E);
    bucket_count<<<NBUK, 256, 0, stream>>>(bke, boff, cnt16, dis, btot, E);
    scan1<<<1, 256, 0, stream>>>(btot, bbase, bsums, NBUK);
    fill_enc<<<NBUK + ENC_BLOCKS, 256, 0, stream>>>(bke, boff, bbase, cnt16, offs, srcs, E,
                                                    x, encW, encb, dis, ht1);

    __half* hin = ht1;
    __half* hot = ht2;
    for (int i = 0; i < NLAYERS; ++i) {
        layer_kernel<<<NBLK, 256, 0, stream>>>(hin, offs, cnt16, (const int4*)srcs, dis,
                                               wfrag + (size_t)i * 512,
                                               convb + (size_t)i * HD,
                                               hot, (i < NLAYERS - 1) ? 1 : 0);
        __half* t = hin; hin = hot; hot = t;
    }

    heads_kernel<<<NH_BLOCKS + N_GRAPHS * 4, 256, 0, stream>>>(hin, nodeW, nodeb, out,
                                                               start, gpart);
    global_head<<<N_GRAPHS, 64, 0, stream>>>(gpart, start, g1W, g1b, g2W, g2b, out + (size_t)N * NT);
}

// Round 17
// 207.151 us; speedup vs baseline: 1.1988x; 1.0894x over previous
//
#include <hip/hip_runtime.h>
#include <hip/hip_fp16.h>

#define N_NODES 100000
#define N_EDGES 1250000
#define N_GRAPHS 64
#define F_INN 29
#define HD 64
#define NT 6
#define GT 4
#define NLAYERS 4
#define RECS_CAP 3000000  // >= E + 15*N worst-case padded size
#define NBLK 1563         // ceil(N_NODES / 64) dest-buckets (layer)
#define NBUK 782          // ceil(N_NODES / 128) CSR-build buckets
#define HGRID 256         // blocks in hist/scatter (edge partition)
#define GB_BLOCKS 391     // ceil(N/256) graph_bounds sections
#define ENC_BLOCKS 6250   // N/16 encoder sections
#define NH_BLOCKS 3125    // ceil(N/32) node-head sections

typedef __attribute__((ext_vector_type(8))) _Float16 f16x8;
typedef __attribute__((ext_vector_type(4))) float f32x4;

// ---------------- fused build + misc kernel ----------------
// sections: [0,HGRID) hist; [HGRID,HGRID+4) prepack_W; HGRID+4 zero pad rows;
// [HGRID+5, HGRID+5+GB_BLOCKS) graph_bounds.
__global__ void hist1_misc(const int* __restrict__ col, int* __restrict__ ghistT, int E,
                           const float* __restrict__ convW, uint4* __restrict__ wfrag,
                           __half* __restrict__ ht1, __half* __restrict__ ht2,
                           const int* __restrict__ batch, int* __restrict__ start) {
    __shared__ int lh[NBUK];
    int tid = threadIdx.x, b = blockIdx.x;
    if (b < HGRID) {
        for (int i = tid; i < NBUK; i += 256) lh[i] = 0;
        __syncthreads();
        for (int e = b * 256 + tid; e < E; e += HGRID * 256) atomicAdd(&lh[col[e] >> 7], 1);
        __syncthreads();
        for (int i = tid; i < NBUK; i += 256) ghistT[i * 256 + b] = lh[i];
    } else if (b < HGRID + 4) {
        // prepack conv weights into MFMA B-fragment order (fp16)
        int layer = b - HGRID;
        const float* W = convW + (size_t)layer * HD * HD;
        uint4* out = wfrag + (size_t)layer * 512;
        for (int s = tid; s < 512; s += 256) {
            int jt = s >> 7, ks = (s >> 6) & 1, l = s & 63;
            int j = jt * 16 + (l & 15);
            int k0 = ks * 32 + (l >> 4) * 8;
            __align__(16) __half hh[8];
            #pragma unroll
            for (int i = 0; i < 8; ++i) hh[i] = __float2half_rn(W[(size_t)(k0 + i) * HD + j]);
            out[s] = *reinterpret_cast<const uint4*>(hh);
        }
    } else if (b == HGRID + 4) {
        if (tid < HD) ht1[(size_t)N_NODES * HD + tid] = __float2half_rn(0.f);
        else if (tid < 2 * HD) ht2[(size_t)N_NODES * HD + (tid - HD)] = __float2half_rn(0.f);
    } else {
        int i = (b - HGRID - 5) * 256 + tid;
        if (i < N_NODES) {
            int bb = batch[i];
            if (i == 0) {
                for (int g = 0; g <= bb; ++g) start[g] = 0;
            } else {
                int pb = batch[i - 1];
                if (pb != bb) for (int g = pb + 1; g <= bb; ++g) start[g] = i;
            }
            if (i == N_NODES - 1) {
                for (int g = bb + 1; g <= N_GRAPHS; ++g) start[g] = N_NODES;
            }
        }
    }
}

// per-bucket exclusive scan over the 256 block counts; tot[k] = bucket total
__global__ void hist_colscan(int* __restrict__ ghistT, int* __restrict__ tot) {
    __shared__ int wsum[4];
    int k = blockIdx.x, tid = threadIdx.x;
    int v = ghistT[k * 256 + tid];
    int incl = v;
    int lane = tid & 63;
    #pragma unroll
    for (int off = 1; off < 64; off <<= 1) {
        int t = __shfl_up(incl, (unsigned)off, 64);
        if (lane >= off) incl += t;
    }
    if (lane == 63) wsum[tid >> 6] = incl;
    __syncthreads();
    int woff = 0;
    for (int w = 0; w < (tid >> 6); ++w) woff += wsum[w];
    ghistT[k * 256 + tid] = woff + incl - v;  // exclusive
    if (tid == 255) tot[k] = woff + incl;
}

// scatter edges into bucket segments; boff (scan of tot) computed in-block,
// block 0 publishes it for bucket_count/fill_enc
__global__ void scatter_buckets(const int* __restrict__ row, const int* __restrict__ col,
                                const int* __restrict__ ghistT, const int* __restrict__ tot,
                                int* __restrict__ boff,
                                unsigned* __restrict__ bke, int E) {
    __shared__ int boffL[NBUK];
    __shared__ int cur[NBUK];
    __shared__ int wsum[4];
    int tid = threadIdx.x, b = blockIdx.x;
    // exclusive scan of tot[0..NBUK) (<=1024 elems)
    {
        int base = tid * 4;
        int v0 = (base + 0 < NBUK) ? tot[base + 0] : 0;
        int v1 = (base + 1 < NBUK) ? tot[base + 1] : 0;
        int v2 = (base + 2 < NBUK) ? tot[base + 2] : 0;
        int v3 = (base + 3 < NBUK) ? tot[base + 3] : 0;
        int tsum = v0 + v1 + v2 + v3;
        int incl = tsum;
        int lane = tid & 63;
        #pragma unroll
        for (int off = 1; off < 64; off <<= 1) {
            int t = __shfl_up(incl, (unsigned)off, 64);
            if (lane >= off) incl += t;
        }
        if (lane == 63) wsum[tid >> 6] = incl;
        __syncthreads();
        int woff = 0;
        for (int w = 0; w < (tid >> 6); ++w) woff += wsum[w];
        int run = woff + incl - tsum;
        if (base + 0 < NBUK) boffL[base + 0] = run; run += v0;
        if (base + 1 < NBUK) boffL[base + 1] = run; run += v1;
        if (base + 2 < NBUK) boffL[base + 2] = run; run += v2;
        if (base + 3 < NBUK) boffL[base + 3] = run;
    }
    __syncthreads();
    for (int i = tid; i < NBUK; i += 256) {
        cur[i] = ghistT[i * 256 + b] + boffL[i];
        if (b == 0) boff[i] = boffL[i];
    }
    __syncthreads();
    for (int e = b * 256 + tid; e < E; e += HGRID * 256) {
        int c = col[e];
        int pos = atomicAdd(&cur[c >> 7], 1);  // LDS atomic
        bke[pos] = (unsigned)row[e] | ((unsigned)(c & 127) << 25);
    }
}

// per-bucket LDS count -> cnt16, dis, and bucket padded total btot[k]
__global__ void bucket_count(const unsigned* __restrict__ bke, const int* __restrict__ boff,
                             int* __restrict__ cnt16, float* __restrict__ dis,
                             int* __restrict__ btot, int E) {
    __shared__ int lc[128];
    __shared__ int red[2];
    int k = blockIdx.x, tid = threadIdx.x;
    if (tid < 128) lc[tid] = 0;
    __syncthreads();
    int s = boff[k];
    int t = (k == NBUK - 1) ? E : boff[k + 1];
    for (int i = s + tid; i < t; i += 256) atomicAdd(&lc[bke[i] >> 25], 1);  // LDS atomic
    __syncthreads();
    int c16 = 0;
    if (tid < 128) {
        int node = k * 128 + tid;
        if (node < N_NODES) {
            int c = lc[tid];
            c16 = (c + 15) & ~15;
            cnt16[node] = c16;
            dis[node] = rsqrtf((float)(c + 1));
        }
        // wave-reduce c16 over the 2 active waves
        int sum = c16;
        #pragma unroll
        for (int off = 1; off < 64; off <<= 1) sum += __shfl_xor(sum, off, 64);
        if ((tid & 63) == 0) red[tid >> 6] = sum;
    }
    __syncthreads();
    if (tid == 0) btot[k] = red[0] + red[1];
}

// fused: per-bucket CSR fill (+offs via LDS scan, bbase via block reduction
// over btot, +pads)  AND  encoder sections
__global__ void fill_enc(const unsigned* __restrict__ bke, const int* __restrict__ boff,
                         const int* __restrict__ btot, const int* __restrict__ cnt16,
                         int* __restrict__ offs, int* __restrict__ srcs, int E,
                         const float* __restrict__ x, const float* __restrict__ encW,
                         const float* __restrict__ encb, const float* __restrict__ dis,
                         __half* __restrict__ ht) {
    int tid = threadIdx.x;
    int b = blockIdx.x;
    if (b < NBUK) {
        __shared__ int offsL[128];
        __shared__ int cur[128];
        __shared__ int wtot[2];
        __shared__ int wred[4];
        int k = b;
        // bbase[k] = sum of btot[0..k)
        int partial = 0;
        for (int i = tid; i < k; i += 256) partial += btot[i];
        {
            int lane = tid & 63;
            #pragma unroll
            for (int off = 1; off < 64; off <<= 1) partial += __shfl_xor(partial, off, 64);
            if (lane == 0) wred[tid >> 6] = partial;
        }
        __syncthreads();
        int bbasek = wred[0] + wred[1] + wred[2] + wred[3];
        int v = 0, incl = 0;
        if (tid < 128) {
            int node = k * 128 + tid;
            v = (node < N_NODES) ? cnt16[node] : 0;
            incl = v;
            int lane = tid & 63;
            #pragma unroll
            for (int off = 1; off < 64; off <<= 1) {
                int t = __shfl_up(incl, (unsigned)off, 64);
                if (lane >= off) incl += t;
            }
            if (lane == 63) wtot[tid >> 6] = incl;
        }
        __syncthreads();
        if (tid < 128) {
            int w0 = (tid >= 64) ? wtot[0] : 0;
            int node = k * 128 + tid;
            int o = bbasek + w0 + incl - v;
            offsL[tid] = o;
            cur[tid] = 0;
            if (node < N_NODES) offs[node] = o;
        }
        __syncthreads();
        int s = boff[k];
        int t = (k == NBUK - 1) ? E : boff[k + 1];
        for (int i = s + tid; i < t; i += 256) {
            unsigned u = bke[i];
            int l = u >> 25;
            int r = atomicAdd(&cur[l], 1);  // LDS atomic
            srcs[offsL[l] + r] = (int)(u & 0x01FFFFFFu);
        }
        __syncthreads();
        if (tid < 128) {
            int node = k * 128 + tid;
            if (node < N_NODES) {
                int c = cur[tid];
                int c16 = (c + 15) & ~15;
                int base = offsL[tid];
                for (int p = base + c; p < base + c16; ++p) srcs[p] = N_NODES;  // pad
            }
        }
    } else {
        // encoder: ht = fp16( dis * relu(x @ encW + encb) )
        __shared__ float Ws[F_INN * HD];
        __shared__ float bs[HD];
        __shared__ float xs[16 * F_INN];
        for (int i = tid; i < F_INN * HD; i += 256) Ws[i] = encW[i];
        if (tid < HD) bs[tid] = encb[tid];
        int n0 = (b - NBUK) * 16;
        for (int i = tid; i < 16 * F_INN; i += 256) {
            int nn = n0 + i / F_INN;
            xs[i] = (nn < N_NODES) ? x[(size_t)nn * F_INN + (i % F_INN)] : 0.f;
        }
        __syncthreads();
        #pragma unroll
        for (int it = 0; it < 4; ++it) {
            int l = it * 4 + (tid >> 6);
            int j = tid & 63;
            int nn = n0 + l;
            if (nn < N_NODES) {
                float a = bs[j];
                #pragma unroll
                for (int k = 0; k < F_INN; ++k) a = fmaf(xs[l * F_INN + k], Ws[k * HD + j], a);
                ht[(size_t)nn * HD + j] = __float2half_rn(dis[nn] * fmaxf(a, 0.f));
            }
        }
    }
}

// ---------------- GCN layer ----------------

#define H2(u) (*reinterpret_cast<const __half2*>(&(u)))
// 16B row slice load (8 halfs at fh8)
#define ROWQ(src) (*reinterpret_cast<const uint4*>(&ht[(size_t)(src) * HD + fh8]))
// 4-deep fp16 tree over 4 rows at half2 slot c, then fp32 accumulate into a0/a1
#define ACCQ(c, idx0, idx1) { \
    __half2 t0 = __hadd2(__hadd2(H2(r0.c), H2(r1.c)), __hadd2(H2(r2.c), H2(r3.c))); \
    __half2 t1 = __hadd2(__hadd2(H2(r4.c), H2(r5.c)), __hadd2(H2(r6.c), H2(r7.c))); \
    float2 f0 = __half22float2(t0); \
    float2 f1 = __half22float2(t1); \
    acc[idx0] += f0.x + f1.x; acc[idx1] += f0.y + f1.y; }

// Bucketed GCN layer, barrier-free main path: block owns 64 dests; quarter-wave
// walks 4 dests' padded CSR slots (16/group). Each quarter's 16 lanes split into
// two 8-lane subsets; each subset loads 8 rows at 16B/lane (8 load issues/group,
// 16 rows in flight). Flush merges subsets via shfl_xor(8), adds pre-staged self
// row in fp32, stores fp16 agg row. MFMA wave-local (wave = node-tile).
__global__ void layer_kernel(const __half* __restrict__ ht,
                             const int* __restrict__ offs, const int* __restrict__ cnt16,
                             const int4* __restrict__ srcs4,
                             const float* __restrict__ dis,
                             const uint4* __restrict__ wfragL, const float* __restrict__ bias,
                             __half* __restrict__ hout, int scaleOut) {
    __shared__ uint4 WfS[512];        // 8KB B-fragments (all j-tiles)
    __shared__ __half aggS[64 * 72];  // 64 agg rows, stride 72 halfs
    __shared__ int offsS[64];
    __shared__ int cntS[64];
    __shared__ float disS[64];
    __shared__ float biasS[64];
    int tid = threadIdx.x;
    int b = blockIdx.x;
    WfS[tid] = wfragL[tid];
    WfS[tid + 256] = wfragL[tid + 256];
    if (tid < 64) {
        int d = b * 64 + tid;
        biasS[tid] = bias[tid];
        if (d < N_NODES) {
            offsS[tid] = offs[d];
            cntS[tid] = cnt16[d];
            disS[tid] = dis[d];
        } else {
            offsS[tid] = offs[N_NODES - 1] + cnt16[N_NODES - 1];
            cntS[tid] = 0;
            disS[tid] = 0.f;
        }
    }
    __syncthreads();  // the only block barrier (staging)

    int wave = tid >> 6;
    int lane = tid & 63;
    int q = lane >> 4;
    int lane16 = lane & 15;
    int sub = lane16 >> 3;        // slot-subset 0/1 within quarter
    int fh8 = (lane16 & 7) * 8;   // feature offset in halfs (16B slice)

    int l0 = wave * 16 + q * 4;
    // pre-stage self rows: each subset stages 2 of the quarter's 4 rows (16B/lane)
    {
        int nbase = b * 64 + l0;
        int d0 = sub * 2, d1 = sub * 2 + 1;
        *reinterpret_cast<uint4*>(&aggS[(l0 + d0) * 72 + fh8]) =
            *reinterpret_cast<const uint4*>(&ht[(size_t)min(nbase + d0, N_NODES) * HD + fh8]);
        *reinterpret_cast<uint4*>(&aggS[(l0 + d1) * 72 + fh8]) =
            *reinterpret_cast<const uint4*>(&ht[(size_t)min(nbase + d1, N_NODES) * HD + fh8]);
    }
    int s = offsS[l0];
    int e = offsS[l0 + 3] + cntS[l0 + 3];
    int dcur = l0;
    int nb = offsS[l0] + cntS[l0];
    float acc[8] = {0.f, 0.f, 0.f, 0.f, 0.f, 0.f, 0.f, 0.f};

    // flush dest d: merge subsets (xor-8), add staged self row (fp32), store fp16
    auto flush = [&](int d) {
        float a0 = acc[0] + __shfl_xor(acc[0], 8, 64);
        float a1 = acc[1] + __shfl_xor(acc[1], 8, 64);
        float a2 = acc[2] + __shfl_xor(acc[2], 8, 64);
        float a3 = acc[3] + __shfl_xor(acc[3], 8, 64);
        float a4 = acc[4] + __shfl_xor(acc[4], 8, 64);
        float a5 = acc[5] + __shfl_xor(acc[5], 8, 64);
        float a6 = acc[6] + __shfl_xor(acc[6], 8, 64);
        float a7 = acc[7] + __shfl_xor(acc[7], 8, 64);
        if (sub == 0) {
            uint4 sv = *reinterpret_cast<uint4*>(&aggS[d * 72 + fh8]);
            float2 s0 = __half22float2(H2(sv.x));
            float2 s1 = __half22float2(H2(sv.y));
            float2 s2 = __half22float2(H2(sv.z));
            float2 s3 = __half22float2(H2(sv.w));
            __half2 h0 = __floats2half2_rn(a0 + s0.x, a1 + s0.y);
            __half2 h1 = __floats2half2_rn(a2 + s1.x, a3 + s1.y);
            __half2 h2 = __floats2half2_rn(a4 + s2.x, a5 + s2.y);
            __half2 h3 = __floats2half2_rn(a6 + s3.x, a7 + s3.y);
            uint4 w;
            w.x = *(unsigned*)&h0;
            w.y = *(unsigned*)&h1;
            w.z = *(unsigned*)&h2;
            w.w = *(unsigned*)&h3;
            *reinterpret_cast<uint4*>(&aggS[d * 72 + fh8]) = w;
        }
        #pragma unroll
        for (int i = 0; i < 8; ++i) acc[i] = 0.f;
    };

    // software-pipelined gather: indices for group p prefetched at p-16
    int4 i0, i1, i2, i3;
    if (s < e) {
        int base = s >> 2;
        i0 = srcs4[base + 0];
        i1 = srcs4[base + 1];
        i2 = srcs4[base + 2];
        i3 = srcs4[base + 3];
    }
    for (int p = s; p < e; p += 16) {
        // subset 0 -> slots p..p+7 (i0,i1); subset 1 -> slots p+8..p+15 (i2,i3)
        int4 ia = sub ? i2 : i0;
        int4 ib = sub ? i3 : i1;
        uint4 r0 = ROWQ(ia.x), r1 = ROWQ(ia.y), r2 = ROWQ(ia.z), r3 = ROWQ(ia.w);
        uint4 r4 = ROWQ(ib.x), r5 = ROWQ(ib.y), r6 = ROWQ(ib.z), r7 = ROWQ(ib.w);
        // prefetch next group's indices
        int pn = p + 16;
        if (pn < e) {
            int base = pn >> 2;
            i0 = srcs4[base + 0];
            i1 = srcs4[base + 1];
            i2 = srcs4[base + 2];
            i3 = srcs4[base + 3];
        }
        // flush finished dest(s) before accumulating this group
        while (p >= nb) {
            flush(dcur);
            ++dcur;
            nb = offsS[dcur] + cntS[dcur];
        }
        ACCQ(x, 0, 1);
        ACCQ(y, 2, 3);
        ACCQ(z, 4, 5);
        ACCQ(w, 6, 7);
    }
    while (dcur <= l0 + 3) {
        flush(dcur);
        ++dcur;
    }

    // WAVE-LOCAL MFMA: wave = node-tile; A row = wave*16 + (lane&15),
    // k = ks*32 + (lane>>4)*8 + i; B = j-tile jt (all 4). No barrier needed.
    f32x4 c0 = {0.f, 0.f, 0.f, 0.f}, c1 = c0, c2 = c0, c3 = c0;
    #pragma unroll
    for (int ks = 0; ks < 2; ++ks) {
        f16x8 a = *reinterpret_cast<const f16x8*>(
            &aggS[(wave * 16 + (lane & 15)) * 72 + ks * 32 + (lane >> 4) * 8]);
        f16x8 b0 = *reinterpret_cast<const f16x8*>(&WfS[(0 * 2 + ks) * 64 + lane]);
        c0 = __builtin_amdgcn_mfma_f32_16x16x32_f16(a, b0, c0, 0, 0, 0);
        f16x8 b1 = *reinterpret_cast<const f16x8*>(&WfS[(1 * 2 + ks) * 64 + lane]);
        c1 = __builtin_amdgcn_mfma_f32_16x16x32_f16(a, b1, c1, 0, 0, 0);
        f16x8 b2 = *reinterpret_cast<const f16x8*>(&WfS[(2 * 2 + ks) * 64 + lane]);
        c2 = __builtin_amdgcn_mfma_f32_16x16x32_f16(a, b2, c2, 0, 0, 0);
        f16x8 b3 = *reinterpret_cast<const f16x8*>(&WfS[(3 * 2 + ks) * 64 + lane]);
        c3 = __builtin_amdgcn_mfma_f32_16x16x32_f16(a, b3, c3, 0, 0, 0);
    }
    // epilogue: D col = lane&15 (j within tile jt), row = (lane>>4)*4 + i
    #pragma unroll
    for (int jt = 0; jt < 4; ++jt) {
        f32x4 c = (jt == 0) ? c0 : (jt == 1) ? c1 : (jt == 2) ? c2 : c3;
        int j = jt * 16 + (lane & 15);
        float bj = biasS[j];
        #pragma unroll
        for (int i = 0; i < 4; ++i) {
            int rl = wave * 16 + (lane >> 4) * 4 + i;
            int node = b * 64 + rl;
            if (node < N_NODES) {
                float dn = disS[rl];
                float o = fmaxf(fmaf(dn, c[i], bj), 0.f);
                if (scaleOut) o *= dn;
                hout[(size_t)node * HD + j] = __float2half_rn(o);
            }
        }
    }
}

// fused heads: sections [0,NH_BLOCKS) node head; rest pool quarters
__global__ void heads_kernel(const __half* __restrict__ h, const float* __restrict__ W,
                             const float* __restrict__ bb, float* __restrict__ out,
                             const int* __restrict__ start, float* __restrict__ gpart) {
    int tid = threadIdx.x;
    int b = blockIdx.x;
    if (b < NH_BLOCKS) {
        __shared__ float Ws[HD * NT];
        __shared__ float bs[NT];
        __shared__ float hs[32 * 65];
        for (int i = tid; i < HD * NT; i += 256) Ws[i] = W[i];
        if (tid < NT) bs[tid] = bb[tid];
        int n0 = b * 32;
        const unsigned* hrow = reinterpret_cast<const unsigned*>(&h[(size_t)n0 * HD]);
        for (int i = tid; i < 32 * HD / 2; i += 256) {
            unsigned u = hrow[i];
            float2 f = __half22float2(*reinterpret_cast<const __half2*>(&u));
            int el = i * 2;
            int row = el >> 6, colc = el & 63;
            hs[row * 65 + colc] = f.x;
            hs[row * 65 + colc + 1] = f.y;
        }
        __syncthreads();
        int l = tid >> 3, t = tid & 7;
        int nn = n0 + l;
        if (nn < N_NODES && t < NT) {
            float a = bs[t];
            #pragma unroll
            for (int k = 0; k < HD; ++k) a = fmaf(hs[l * 65 + k], Ws[k * NT + t], a);
            out[(size_t)nn * NT + t] = a;
        }
    } else {
        __shared__ float red[4][HD];
        int pb = b - NH_BLOCKS;
        int g = pb >> 2, q = pb & 3;
        int s0 = start[g], e0 = start[g + 1];
        int len = e0 - s0;
        int qs = s0 + (len * q) / 4;
        int qe = s0 + (len * (q + 1)) / 4;
        int wave = tid >> 6, lane = tid & 63;
        float acc = 0.f;
        for (int r = qs + wave; r < qe; r += 4) acc += __half2float(h[(size_t)r * HD + lane]);
        red[wave][lane] = acc;
        __syncthreads();
        if (wave == 0)
            gpart[(size_t)pb * HD + lane] =
                red[0][lane] + red[1][lane] + red[2][lane] + red[3][lane];
    }
}

__global__ void global_head(const float* __restrict__ gpart, const int* __restrict__ start,
                            const float* __restrict__ g1W, const float* __restrict__ g1b,
                            const float* __restrict__ g2W, const float* __restrict__ g2b,
                            float* __restrict__ out) {
    __shared__ float rS[HD];
    int g = blockIdx.x;
    int j = threadIdx.x;  // 64
    int cnt = start[g + 1] - start[g];
    float inv = 1.f / fmaxf((float)cnt, 1.f);
    rS[j] = (gpart[(size_t)(4 * g + 0) * HD + j] + gpart[(size_t)(4 * g + 1) * HD + j] +
             gpart[(size_t)(4 * g + 2) * HD + j] + gpart[(size_t)(4 * g + 3) * HD + j]) * inv;
    __syncthreads();
    float a = g1b[j];
    #pragma unroll
    for (int k = 0; k < HD; ++k) a = fmaf(rS[k], g1W[k * HD + j], a);
    a = fmaxf(a, 0.f);
    float o0 = a * g2W[j * GT + 0];
    float o1 = a * g2W[j * GT + 1];
    float o2 = a * g2W[j * GT + 2];
    float o3 = a * g2W[j * GT + 3];
    #pragma unroll
    for (int off = 1; off < 64; off <<= 1) {
        o0 += __shfl_xor(o0, off, 64);
        o1 += __shfl_xor(o1, off, 64);
        o2 += __shfl_xor(o2, off, 64);
        o3 += __shfl_xor(o3, off, 64);
    }
    if (j == 0) {
        out[g * GT + 0] = o0 + g2b[0];
        out[g * GT + 1] = o1 + g2b[1];
        out[g * GT + 2] = o2 + g2b[2];
        out[g * GT + 3] = o3 + g2b[3];
    }
}

// ---------------- launch ----------------

extern "C" void kernel_launch(void* const* d_in, const int* in_sizes, int n_in,
                              void* d_out, int out_size, void* d_ws, size_t ws_size,
                              hipStream_t stream) {
    const float* x    = (const float*)d_in[0];
    const int*   ei   = (const int*)d_in[1];
    const int*   batch= (const int*)d_in[2];
    const float* encW = (const float*)d_in[3];
    const float* encb = (const float*)d_in[4];
    const float* convW= (const float*)d_in[5];
    const float* convb= (const float*)d_in[6];
    const float* nodeW= (const float*)d_in[7];
    const float* nodeb= (const float*)d_in[8];
    const float* g1W  = (const float*)d_in[9];
    const float* g1b  = (const float*)d_in[10];
    const float* g2W  = (const float*)d_in[11];
    const float* g2b  = (const float*)d_in[12];
    float* out = (float*)d_out;

    const int N = N_NODES, E = N_EDGES;

    char* ws = (char*)d_ws;
    size_t off = 0;
    auto alloc = [&](size_t bytes) -> void* {
        void* p = ws + off;
        off += (bytes + 255) & ~(size_t)255;
        return p;
    };
    // all buffers fully written before read — no memset needed
    int*    ghistT = (int*)alloc((size_t)NBUK * 256 * 4);
    int*    tot    = (int*)alloc((size_t)NBUK * 4);
    int*    boff   = (int*)alloc((size_t)NBUK * 4);
    int*    btot   = (int*)alloc((size_t)NBUK * 4);
    unsigned* bke  = (unsigned*)alloc((size_t)E * 4);
    int*    offs   = (int*)alloc((size_t)N * 4);
    int*    cnt16  = (int*)alloc((size_t)N * 4);
    float*  dis    = (float*)alloc((size_t)N * 4);
    int*    start  = (int*)alloc((size_t)(N_GRAPHS + 1) * 4);
    float*  gpart  = (float*)alloc((size_t)N_GRAPHS * 4 * HD * 4);
    uint4*  wfrag  = (uint4*)alloc((size_t)NLAYERS * 512 * 16);
    int*    srcs   = (int*)alloc((size_t)RECS_CAP * 4);
    __half* ht1    = (__half*)alloc((size_t)(N + 1) * HD * 2);  // +1 pad row
    __half* ht2    = (__half*)alloc((size_t)(N + 1) * HD * 2);

    // fused build + misc (hist, prepack, pad rows, graph bounds)
    hist1_misc<<<HGRID + 5 + GB_BLOCKS, 256, 0, stream>>>(ei + E, ghistT, E, convW, wfrag,
                                                          ht1, ht2, batch, start);
    hist_colscan<<<NBUK, 256, 0, stream>>>(ghistT, tot);
    scatter_buckets<<<HGRID, 256, 0, stream>>>(ei, ei + E, ghistT, tot, boff, bke, E);
    bucket_count<<<NBUK, 256, 0, stream>>>(bke, boff, cnt16, dis, btot, E);
    fill_enc<<<NBUK + ENC_BLOCKS, 256, 0, stream>>>(bke, boff, btot, cnt16, offs, srcs, E,
                                                    x, encW, encb, dis, ht1);

    __half* hin = ht1;
    __half* hot = ht2;
    for (int i = 0; i < NLAYERS; ++i) {
        layer_kernel<<<NBLK, 256, 0, stream>>>(hin, offs, cnt16, (const int4*)srcs, dis,
                                               wfrag + (size_t)i * 512,
                                               convb + (size_t)i * HD,
                                               hot, (i < NLAYERS - 1) ? 1 : 0);
        __half* t = hin; hin = hot; hot = t;
    }

    heads_kernel<<<NH_BLOCKS + N_GRAPHS * 4, 256, 0, stream>>>(hin, nodeW, nodeb, out,
                                                               start, gpart);
    global_head<<<N_GRAPHS, 64, 0, stream>>>(gpart, start, g1W, g1b, g2W, g2b, out + (size_t)N * NT);
}